// Round 2
// baseline (15041.516 us; speedup 1.0000x reference)
//
#include <hip/hip_runtime.h>
#include <hip/hip_bf16.h>
#include <stdint.h>

#define HH 256
#define BN_EPS 1e-5f

static inline int cdiv(int a, int b) { return (a + b - 1) / b; }

// ---------------- embed: h = x_atom@ae_w + ae_b + x_pe@pe_w + pe_b ----------------
__global__ void embed_kernel(const float* __restrict__ xa, const float* __restrict__ xp,
                             const float* __restrict__ aw, const float* __restrict__ ab,
                             const float* __restrict__ pw, const float* __restrict__ pb,
                             float* __restrict__ h, int N) {
    int n = blockIdx.x;
    int c = threadIdx.x;
    if (n >= N) return;
    float acc = ab[c] + pb[c];
#pragma unroll
    for (int k = 0; k < 9; ++k) acc += xa[n * 9 + k] * aw[k * HH + c];
#pragma unroll
    for (int k = 0; k < 8; ++k) acc += xp[n * 8 + k] * pw[k * HH + c];
    h[(size_t)n * HH + c] = acc;
}

// ---------------- copy (z = h), vectorized ----------------
__global__ void copy_kernel(const float* __restrict__ src, float* __restrict__ dst, int n4) {
    int i = blockIdx.x * blockDim.x + threadIdx.x;
    int stride = gridDim.x * blockDim.x;
    for (; i < n4; i += stride)
        ((float4*)dst)[i] = ((const float4*)src)[i];
}

// ---------------- scatter-add: z[dst] += h[src], one wave per edge ----------------
__global__ void scatter_add_kernel(const float* __restrict__ h, const int* __restrict__ ei,
                                   float* __restrict__ z, int E) {
    int gid = blockIdx.x * blockDim.x + threadIdx.x;
    int e = gid >> 6;
    int lane = gid & 63;
    if (e >= E) return;
    int s = ei[e];
    int d = ei[(size_t)E + e];
    float4 v = *(const float4*)&h[(size_t)s * HH + lane * 4];
    float* zp = &z[(size_t)d * HH + lane * 4];
    atomicAdd(zp + 0, v.x);
    atomicAdd(zp + 1, v.y);
    atomicAdd(zp + 2, v.z);
    atomicAdd(zp + 3, v.w);
}

// ---------------- f32 GEMM: C[M x ldw] = A[M x 256] @ W[256 x ldw] + bias ----------------
// 64x64 tile per block, 256 threads, each thread 4x4, K-tile 32.
__global__ __launch_bounds__(256) void gemm_kernel(const float* __restrict__ A,
                                                   const float* __restrict__ W,
                                                   const float* __restrict__ bias,
                                                   float* __restrict__ C,
                                                   int M, int ldw) {
    __shared__ float As[64][33];   // padded: conflict-free column reads
    __shared__ float Ws[32][64];
    int tid = threadIdx.x;
    int tx = tid & 15, ty = tid >> 4;
    int row0 = blockIdx.x * 64;
    int col0 = blockIdx.y * 64;
    float acc[4][4] = {};

    for (int k0 = 0; k0 < 256; k0 += 32) {
        // stage A tile (64 x 32)
#pragma unroll
        for (int t = 0; t < 2; ++t) {
            int s = tid + t * 256;
            int m = s >> 3;
            int kq = (s & 7) * 4;
            float4 v = make_float4(0.f, 0.f, 0.f, 0.f);
            if (row0 + m < M) v = *(const float4*)&A[(size_t)(row0 + m) * 256 + k0 + kq];
            As[m][kq + 0] = v.x; As[m][kq + 1] = v.y; As[m][kq + 2] = v.z; As[m][kq + 3] = v.w;
        }
        // stage W tile (32 x 64) — k-major already
#pragma unroll
        for (int t = 0; t < 2; ++t) {
            int s = tid + t * 256;
            int kk = s >> 4;
            int cq = (s & 15) * 4;
            *(float4*)&Ws[kk][cq] = *(const float4*)&W[(size_t)(k0 + kk) * ldw + col0 + cq];
        }
        __syncthreads();
#pragma unroll
        for (int kk = 0; kk < 32; ++kk) {
            float a0 = As[ty * 4 + 0][kk];
            float a1 = As[ty * 4 + 1][kk];
            float a2 = As[ty * 4 + 2][kk];
            float a3 = As[ty * 4 + 3][kk];
            float4 w = *(const float4*)&Ws[kk][tx * 4];
            acc[0][0] += a0 * w.x; acc[0][1] += a0 * w.y; acc[0][2] += a0 * w.z; acc[0][3] += a0 * w.w;
            acc[1][0] += a1 * w.x; acc[1][1] += a1 * w.y; acc[1][2] += a1 * w.z; acc[1][3] += a1 * w.w;
            acc[2][0] += a2 * w.x; acc[2][1] += a2 * w.y; acc[2][2] += a2 * w.z; acc[2][3] += a2 * w.w;
            acc[3][0] += a3 * w.x; acc[3][1] += a3 * w.y; acc[3][2] += a3 * w.z; acc[3][3] += a3 * w.w;
        }
        __syncthreads();
    }

    float4 bv = *(const float4*)&bias[col0 + tx * 4];
#pragma unroll
    for (int j = 0; j < 4; ++j) {
        int row = row0 + ty * 4 + j;
        if (row < M) {
            float4 o = make_float4(acc[j][0] + bv.x, acc[j][1] + bv.y,
                                   acc[j][2] + bv.z, acc[j][3] + bv.w);
            *(float4*)&C[(size_t)row * ldw + col0 + tx * 4] = o;
        }
    }
}

// ---------------- BN helpers ----------------
__global__ void zero_kernel(float* __restrict__ p, int n) {
    int i = blockIdx.x * blockDim.x + threadIdx.x;
    if (i < n) p[i] = 0.f;
}

// per-column sum and sumsq over rows (column-parallel, 128 rows per block)
__global__ void bn_stats_kernel(const float* __restrict__ X, int M, float* __restrict__ stats) {
    int c = threadIdx.x;
    int r0 = blockIdx.x * 128;
    int r1 = min(r0 + 128, M);
    float s = 0.f, s2 = 0.f;
    for (int r = r0; r < r1; ++r) {
        float v = X[(size_t)r * HH + c];
        s += v;
        s2 += v * v;
    }
    atomicAdd(&stats[c], s);
    atomicAdd(&stats[HH + c], s2);
}

__global__ void bn_finalize_kernel(float* __restrict__ stats, const float* __restrict__ g,
                                   const float* __restrict__ b, float invM) {
    int c = threadIdx.x;
    float mu = stats[c] * invM;
    float var = stats[HH + c] * invM - mu * mu;
    float rstd = rsqrtf(var + BN_EPS);
    float sc = rstd * g[c];
    stats[2 * HH + c] = sc;
    stats[3 * HH + c] = b[c] - mu * sc;
}

// y = relu(x*scale[c] + shift[c]) in place; rows are 256 floats (64 float4)
__global__ void bn_apply_relu_kernel(float* __restrict__ X, int n4, const float* __restrict__ stats) {
    int i = blockIdx.x * blockDim.x + threadIdx.x;
    int stride = gridDim.x * blockDim.x;
    for (; i < n4; i += stride) {
        int c4 = (i & 63) * 4;
        float4 v = ((float4*)X)[i];
        float4 sc = *(const float4*)&stats[2 * HH + c4];
        float4 sh = *(const float4*)&stats[3 * HH + c4];
        v.x = fmaxf(v.x * sc.x + sh.x, 0.f);
        v.y = fmaxf(v.y * sc.y + sh.y, 0.f);
        v.z = fmaxf(v.z * sc.z + sh.z, 0.f);
        v.w = fmaxf(v.w * sc.w + sh.w, 0.f);
        ((float4*)X)[i] = v;
    }
}

// ---------------- mean pool per graph (batch sorted, int32 ids) ----------------
__device__ __forceinline__ int lbound(const int* a, int n, int v) {
    int lo = 0, hi = n;
    while (lo < hi) {
        int mid = (lo + hi) >> 1;
        if (a[mid] < v) lo = mid + 1; else hi = mid;
    }
    return lo;
}

__global__ void pool_kernel(const float* __restrict__ Hm, const int* __restrict__ batch,
                            int N, float* __restrict__ pooled) {
    int g = blockIdx.x;
    int c = threadIdx.x;
    int s = lbound(batch, N, g);
    int e = lbound(batch, N, g + 1);
    float acc = 0.f;
    for (int r = s; r < e; ++r) acc += Hm[(size_t)r * HH + c];
    pooled[(size_t)g * HH + c] = acc / (float)max(e - s, 1);
}

// ---------------- launch ----------------
extern "C" void kernel_launch(void* const* d_in, const int* in_sizes, int n_in,
                              void* d_out, int out_size, void* d_ws, size_t ws_size,
                              hipStream_t stream) {
    const float* x_atom = (const float*)d_in[0];
    const float* x_pe   = (const float*)d_in[1];
    const int* ei       = (const int*)d_in[2];     // harness delivers integer inputs as int32
    const int* batch    = (const int*)d_in[3];
    const float* ae_w = (const float*)d_in[4];
    const float* ae_b = (const float*)d_in[5];
    const float* pe_w = (const float*)d_in[6];
    const float* pe_b = (const float*)d_in[7];
    const float* w1  = (const float*)d_in[8];
    const float* b1  = (const float*)d_in[9];
    const float* g1  = (const float*)d_in[10];
    const float* be1 = (const float*)d_in[11];
    const float* w2  = (const float*)d_in[12];
    const float* b2  = (const float*)d_in[13];
    const float* bng = (const float*)d_in[14];
    const float* bnb = (const float*)d_in[15];
    const float* cl1_w = (const float*)d_in[16];
    const float* cl1_b = (const float*)d_in[17];
    const float* clg = (const float*)d_in[18];
    const float* clb = (const float*)d_in[19];
    const float* cl2_w = (const float*)d_in[20];
    const float* cl2_b = (const float*)d_in[21];

    const int N = in_sizes[3];
    const int E = in_sizes[2] / 2;
    const int T = in_sizes[21];
    const int B = out_size / T;
    const int Lnum = in_sizes[9] / HH;

    float* ws = (float*)d_ws;
    float* bufA = ws;
    float* bufB = bufA + (size_t)N * HH;
    float* stats = bufB + (size_t)N * HH;
    float* pooled = stats + 4 * HH;
    float* zc = pooled + (size_t)B * HH;

    const int NH4 = N * (HH / 4);   // float4 count of an N x H buffer
    const int BH4 = B * (HH / 4);

    // embed
    embed_kernel<<<N, HH, 0, stream>>>(x_atom, x_pe, ae_w, ae_b, pe_w, pe_b, bufA, N);

    float* hb = bufA;
    float* zb = bufB;

    dim3 gemm_grid(cdiv(N, 64), HH / 64);
    int copy_blocks = min(4096, cdiv(NH4, 256));
    int scatter_blocks = cdiv(E * 64, 256);

    for (int i = 0; i < Lnum; ++i) {
        const float* w1i = w1 + (size_t)i * HH * HH;
        const float* w2i = w2 + (size_t)i * HH * HH;

        // z = h + segment_sum(h[src] -> dst)
        copy_kernel<<<copy_blocks, 256, 0, stream>>>(hb, zb, NH4);
        scatter_add_kernel<<<scatter_blocks, 256, 0, stream>>>(hb, ei, zb, E);

        // z1 = z @ w1 + b1 -> hb ; BN + relu
        gemm_kernel<<<gemm_grid, 256, 0, stream>>>(zb, w1i, b1 + (size_t)i * HH, hb, N, HH);
        zero_kernel<<<2, 256, 0, stream>>>(stats, 2 * HH);
        bn_stats_kernel<<<cdiv(N, 128), HH, 0, stream>>>(hb, N, stats);
        bn_finalize_kernel<<<1, HH, 0, stream>>>(stats, g1 + (size_t)i * HH, be1 + (size_t)i * HH, 1.f / N);
        bn_apply_relu_kernel<<<copy_blocks, 256, 0, stream>>>(hb, NH4, stats);

        // z2 = z1 @ w2 + b2 -> zb ; BN + relu
        gemm_kernel<<<gemm_grid, 256, 0, stream>>>(hb, w2i, b2 + (size_t)i * HH, zb, N, HH);
        zero_kernel<<<2, 256, 0, stream>>>(stats, 2 * HH);
        bn_stats_kernel<<<cdiv(N, 128), HH, 0, stream>>>(zb, N, stats);
        bn_finalize_kernel<<<1, HH, 0, stream>>>(stats, bng + (size_t)i * HH, bnb + (size_t)i * HH, 1.f / N);
        bn_apply_relu_kernel<<<copy_blocks, 256, 0, stream>>>(zb, NH4, stats);

        // swap: new h is zb
        float* tmp = hb; hb = zb; zb = tmp;
    }

    // global mean pool
    pool_kernel<<<B, HH, 0, stream>>>(hb, batch, N, pooled);

    // classifier: z = relu(BN(pooled @ cl1_w + cl1_b)); out = z @ cl2_w + cl2_b
    dim3 cls_grid1(cdiv(B, 64), HH / 64);
    gemm_kernel<<<cls_grid1, 256, 0, stream>>>(pooled, cl1_w, cl1_b, zc, B, HH);
    zero_kernel<<<2, 256, 0, stream>>>(stats, 2 * HH);
    bn_stats_kernel<<<cdiv(B, 128), HH, 0, stream>>>(zc, B, stats);
    bn_finalize_kernel<<<1, HH, 0, stream>>>(stats, clg, clb, 1.f / B);
    bn_apply_relu_kernel<<<min(4096, cdiv(BH4, 256)), 256, 0, stream>>>(zc, BH4, stats);

    dim3 cls_grid2(cdiv(B, 64), T / 64);
    gemm_kernel<<<cls_grid2, 256, 0, stream>>>(zc, cl2_w, cl2_b, (float*)d_out, B, T);
}

// Round 3
// 2371.396 us; speedup vs baseline: 6.3429x; 6.3429x over previous
//
#include <hip/hip_runtime.h>
#include <hip/hip_bf16.h>
#include <stdint.h>

#define HH 256
#define BN_EPS 1e-5f
#define CHUNK 256

static inline int cdiv(int a, int b) { return (a + b - 1) / b; }

// ---------------- embed: h = x_atom@ae_w + ae_b + x_pe@pe_w + pe_b ----------------
__global__ void embed_kernel(const float* __restrict__ xa, const float* __restrict__ xp,
                             const float* __restrict__ aw, const float* __restrict__ ab,
                             const float* __restrict__ pw, const float* __restrict__ pb,
                             float* __restrict__ h, int N) {
    int n = blockIdx.x;
    int c = threadIdx.x;
    if (n >= N) return;
    float acc = ab[c] + pb[c];
#pragma unroll
    for (int k = 0; k < 9; ++k) acc += xa[n * 9 + k] * aw[k * HH + c];
#pragma unroll
    for (int k = 0; k < 8; ++k) acc += xp[n * 8 + k] * pw[k * HH + c];
    h[(size_t)n * HH + c] = acc;
}

// ---------------- CSR build ----------------
__global__ void zero_int_kernel(int* __restrict__ p, int n) {
    int i = blockIdx.x * blockDim.x + threadIdx.x;
    if (i < n) p[i] = 0;
}

__global__ void hist_kernel(const int* __restrict__ ei, int* __restrict__ deg, int E) {
    int e = blockIdx.x * blockDim.x + threadIdx.x;
    if (e < E) atomicAdd(&deg[ei[(size_t)E + e]], 1);
}

// per-chunk sums
__global__ void ps1_kernel(const int* __restrict__ deg, int* __restrict__ chunkSum, int N) {
    __shared__ int sm[CHUNK];
    int i = blockIdx.x * CHUNK + threadIdx.x;
    sm[threadIdx.x] = (i < N) ? deg[i] : 0;
    __syncthreads();
    for (int off = CHUNK / 2; off > 0; off >>= 1) {
        if (threadIdx.x < off) sm[threadIdx.x] += sm[threadIdx.x + off];
        __syncthreads();
    }
    if (threadIdx.x == 0) chunkSum[blockIdx.x] = sm[0];
}

// exclusive scan of chunk sums (nc <= 256), plus offs[N] = E
__global__ void ps2_kernel(const int* __restrict__ chunkSum, int* __restrict__ chunkOff,
                           int nc, int* __restrict__ offs, int N, int E) {
    __shared__ int sm[CHUNK];
    int t = threadIdx.x;
    int own = (t < nc) ? chunkSum[t] : 0;
    sm[t] = own;
    for (int off = 1; off < CHUNK; off <<= 1) {
        __syncthreads();
        int v = (t >= off) ? sm[t - off] : 0;
        __syncthreads();
        sm[t] += v;
    }
    if (t < nc) chunkOff[t] = sm[t] - own;   // exclusive
    if (t == 0) offs[N] = E;
}

// intra-chunk exclusive scan + chunk offset
__global__ void ps3_kernel(const int* __restrict__ deg, const int* __restrict__ chunkOff,
                           int* __restrict__ offs, int* __restrict__ cursor, int N) {
    __shared__ int sm[CHUNK];
    int t = threadIdx.x;
    int i = blockIdx.x * CHUNK + t;
    int own = (i < N) ? deg[i] : 0;
    sm[t] = own;
    for (int off = 1; off < CHUNK; off <<= 1) {
        __syncthreads();
        int v = (t >= off) ? sm[t - off] : 0;
        __syncthreads();
        sm[t] += v;
    }
    if (i < N) {
        int o = chunkOff[blockIdx.x] + sm[t] - own;
        offs[i] = o;
        cursor[i] = o;
    }
}

__global__ void fill_kernel(const int* __restrict__ ei, int* __restrict__ cursor,
                            int* __restrict__ srcl, int E) {
    int e = blockIdx.x * blockDim.x + threadIdx.x;
    if (e >= E) return;
    int s = ei[e];
    int d = ei[(size_t)E + e];
    int pos = atomicAdd(&cursor[d], 1);
    srcl[pos] = s;
}

// ---------------- aggregation: z[n] = h[n] + sum_{j in in(n)} h[src_j] ----------------
// 4 nodes per block (one wave each); per edge the wave reads a full contiguous 1KB row.
__global__ __launch_bounds__(256) void aggregate_kernel(const float* __restrict__ h,
                                                        const int* __restrict__ offs,
                                                        const int* __restrict__ srcl,
                                                        float* __restrict__ z, int N) {
    int n = blockIdx.x * 4 + (threadIdx.x >> 6);
    int lane = threadIdx.x & 63;
    if (n >= N) return;
    float4 acc = *(const float4*)&h[(size_t)n * HH + lane * 4];
    int s0 = offs[n], s1 = offs[n + 1];
    for (int j = s0; j < s1; ++j) {
        int s = srcl[j];
        float4 v = *(const float4*)&h[(size_t)s * HH + lane * 4];
        acc.x += v.x; acc.y += v.y; acc.z += v.z; acc.w += v.w;
    }
    *(float4*)&z[(size_t)n * HH + lane * 4] = acc;
}

// ---------------- f32 GEMM: C[M x ldw] = A[M x 256] @ W[256 x ldw] + bias ----------------
__global__ __launch_bounds__(256) void gemm_kernel(const float* __restrict__ A,
                                                   const float* __restrict__ W,
                                                   const float* __restrict__ bias,
                                                   float* __restrict__ C,
                                                   int M, int ldw) {
    __shared__ float As[64][33];
    __shared__ float Ws[32][64];
    int tid = threadIdx.x;
    int tx = tid & 15, ty = tid >> 4;
    int row0 = blockIdx.x * 64;
    int col0 = blockIdx.y * 64;
    float acc[4][4] = {};

    for (int k0 = 0; k0 < 256; k0 += 32) {
#pragma unroll
        for (int t = 0; t < 2; ++t) {
            int s = tid + t * 256;
            int m = s >> 3;
            int kq = (s & 7) * 4;
            float4 v = make_float4(0.f, 0.f, 0.f, 0.f);
            if (row0 + m < M) v = *(const float4*)&A[(size_t)(row0 + m) * 256 + k0 + kq];
            As[m][kq + 0] = v.x; As[m][kq + 1] = v.y; As[m][kq + 2] = v.z; As[m][kq + 3] = v.w;
        }
#pragma unroll
        for (int t = 0; t < 2; ++t) {
            int s = tid + t * 256;
            int kk = s >> 4;
            int cq = (s & 15) * 4;
            *(float4*)&Ws[kk][cq] = *(const float4*)&W[(size_t)(k0 + kk) * ldw + col0 + cq];
        }
        __syncthreads();
#pragma unroll
        for (int kk = 0; kk < 32; ++kk) {
            float a0 = As[ty * 4 + 0][kk];
            float a1 = As[ty * 4 + 1][kk];
            float a2 = As[ty * 4 + 2][kk];
            float a3 = As[ty * 4 + 3][kk];
            float4 w = *(const float4*)&Ws[kk][tx * 4];
            acc[0][0] += a0 * w.x; acc[0][1] += a0 * w.y; acc[0][2] += a0 * w.z; acc[0][3] += a0 * w.w;
            acc[1][0] += a1 * w.x; acc[1][1] += a1 * w.y; acc[1][2] += a1 * w.z; acc[1][3] += a1 * w.w;
            acc[2][0] += a2 * w.x; acc[2][1] += a2 * w.y; acc[2][2] += a2 * w.z; acc[2][3] += a2 * w.w;
            acc[3][0] += a3 * w.x; acc[3][1] += a3 * w.y; acc[3][2] += a3 * w.z; acc[3][3] += a3 * w.w;
        }
        __syncthreads();
    }

    float4 bv = *(const float4*)&bias[col0 + tx * 4];
#pragma unroll
    for (int j = 0; j < 4; ++j) {
        int row = row0 + ty * 4 + j;
        if (row < M) {
            float4 o = make_float4(acc[j][0] + bv.x, acc[j][1] + bv.y,
                                   acc[j][2] + bv.z, acc[j][3] + bv.w);
            *(float4*)&C[(size_t)row * ldw + col0 + tx * 4] = o;
        }
    }
}

// ---------------- BN helpers ----------------
__global__ void zero_kernel(float* __restrict__ p, int n) {
    int i = blockIdx.x * blockDim.x + threadIdx.x;
    if (i < n) p[i] = 0.f;
}

__global__ void bn_stats_kernel(const float* __restrict__ X, int M, float* __restrict__ stats) {
    int c = threadIdx.x;
    int r0 = blockIdx.x * 128;
    int r1 = min(r0 + 128, M);
    float s = 0.f, s2 = 0.f;
    for (int r = r0; r < r1; ++r) {
        float v = X[(size_t)r * HH + c];
        s += v;
        s2 += v * v;
    }
    atomicAdd(&stats[c], s);
    atomicAdd(&stats[HH + c], s2);
}

__global__ void bn_finalize_kernel(float* __restrict__ stats, const float* __restrict__ g,
                                   const float* __restrict__ b, float invM) {
    int c = threadIdx.x;
    float mu = stats[c] * invM;
    float var = stats[HH + c] * invM - mu * mu;
    float rstd = rsqrtf(var + BN_EPS);
    float sc = rstd * g[c];
    stats[2 * HH + c] = sc;
    stats[3 * HH + c] = b[c] - mu * sc;
}

__global__ void bn_apply_relu_kernel(float* __restrict__ X, int n4, const float* __restrict__ stats) {
    int i = blockIdx.x * blockDim.x + threadIdx.x;
    int stride = gridDim.x * blockDim.x;
    for (; i < n4; i += stride) {
        int c4 = (i & 63) * 4;
        float4 v = ((float4*)X)[i];
        float4 sc = *(const float4*)&stats[2 * HH + c4];
        float4 sh = *(const float4*)&stats[3 * HH + c4];
        v.x = fmaxf(v.x * sc.x + sh.x, 0.f);
        v.y = fmaxf(v.y * sc.y + sh.y, 0.f);
        v.z = fmaxf(v.z * sc.z + sh.z, 0.f);
        v.w = fmaxf(v.w * sc.w + sh.w, 0.f);
        ((float4*)X)[i] = v;
    }
}

// ---------------- mean pool per graph (batch sorted, int32 ids) ----------------
__device__ __forceinline__ int lbound(const int* a, int n, int v) {
    int lo = 0, hi = n;
    while (lo < hi) {
        int mid = (lo + hi) >> 1;
        if (a[mid] < v) lo = mid + 1; else hi = mid;
    }
    return lo;
}

__global__ void pool_kernel(const float* __restrict__ Hm, const int* __restrict__ batch,
                            int N, float* __restrict__ pooled) {
    int g = blockIdx.x;
    int c = threadIdx.x;
    int s = lbound(batch, N, g);
    int e = lbound(batch, N, g + 1);
    float acc = 0.f;
    for (int r = s; r < e; ++r) acc += Hm[(size_t)r * HH + c];
    pooled[(size_t)g * HH + c] = acc / (float)max(e - s, 1);
}

// ---------------- launch ----------------
extern "C" void kernel_launch(void* const* d_in, const int* in_sizes, int n_in,
                              void* d_out, int out_size, void* d_ws, size_t ws_size,
                              hipStream_t stream) {
    const float* x_atom = (const float*)d_in[0];
    const float* x_pe   = (const float*)d_in[1];
    const int* ei       = (const int*)d_in[2];
    const int* batch    = (const int*)d_in[3];
    const float* ae_w = (const float*)d_in[4];
    const float* ae_b = (const float*)d_in[5];
    const float* pe_w = (const float*)d_in[6];
    const float* pe_b = (const float*)d_in[7];
    const float* w1  = (const float*)d_in[8];
    const float* b1  = (const float*)d_in[9];
    const float* g1  = (const float*)d_in[10];
    const float* be1 = (const float*)d_in[11];
    const float* w2  = (const float*)d_in[12];
    const float* b2  = (const float*)d_in[13];
    const float* bng = (const float*)d_in[14];
    const float* bnb = (const float*)d_in[15];
    const float* cl1_w = (const float*)d_in[16];
    const float* cl1_b = (const float*)d_in[17];
    const float* clg = (const float*)d_in[18];
    const float* clb = (const float*)d_in[19];
    const float* cl2_w = (const float*)d_in[20];
    const float* cl2_b = (const float*)d_in[21];

    const int N = in_sizes[3];
    const int E = in_sizes[2] / 2;
    const int T = in_sizes[21];
    const int B = out_size / T;
    const int Lnum = in_sizes[9] / HH;
    const int nc = cdiv(N, CHUNK);

    float* ws = (float*)d_ws;
    float* bufA = ws;
    float* bufB = bufA + (size_t)N * HH;
    float* stats = bufB + (size_t)N * HH;
    float* pooled = stats + 4 * HH;
    float* zc = pooled + (size_t)B * HH;
    int* deg = (int*)(zc + (size_t)B * HH);
    int* offs = deg + N;            // N+1
    int* cursor = offs + N + 1;     // N
    int* chunkSum = cursor + N;     // nc (<=256)
    int* chunkOff = chunkSum + 256; // nc
    int* srcl = chunkOff + 256;     // E

    const int NH4 = N * (HH / 4);
    const int BH4 = B * (HH / 4);

    // ---- CSR build (once; edge_index constant across layers) ----
    zero_int_kernel<<<cdiv(N, 256), 256, 0, stream>>>(deg, N);
    hist_kernel<<<cdiv(E, 256), 256, 0, stream>>>(ei, deg, E);
    ps1_kernel<<<nc, CHUNK, 0, stream>>>(deg, chunkSum, N);
    ps2_kernel<<<1, CHUNK, 0, stream>>>(chunkSum, chunkOff, nc, offs, N, E);
    ps3_kernel<<<nc, CHUNK, 0, stream>>>(deg, chunkOff, offs, cursor, N);
    fill_kernel<<<cdiv(E, 256), 256, 0, stream>>>(ei, cursor, srcl, E);

    // embed
    embed_kernel<<<N, HH, 0, stream>>>(x_atom, x_pe, ae_w, ae_b, pe_w, pe_b, bufA, N);

    float* hb = bufA;
    float* zb = bufB;

    dim3 gemm_grid(cdiv(N, 64), HH / 64);
    int copy_blocks = min(4096, cdiv(NH4, 256));

    for (int i = 0; i < Lnum; ++i) {
        const float* w1i = w1 + (size_t)i * HH * HH;
        const float* w2i = w2 + (size_t)i * HH * HH;

        // z = h + segment_sum(h[src] -> dst)  [CSR gather, no atomics]
        aggregate_kernel<<<cdiv(N, 4), 256, 0, stream>>>(hb, offs, srcl, zb, N);

        // z1 = z @ w1 + b1 -> hb ; BN + relu
        gemm_kernel<<<gemm_grid, 256, 0, stream>>>(zb, w1i, b1 + (size_t)i * HH, hb, N, HH);
        zero_kernel<<<2, 256, 0, stream>>>(stats, 2 * HH);
        bn_stats_kernel<<<cdiv(N, 128), HH, 0, stream>>>(hb, N, stats);
        bn_finalize_kernel<<<1, HH, 0, stream>>>(stats, g1 + (size_t)i * HH, be1 + (size_t)i * HH, 1.f / N);
        bn_apply_relu_kernel<<<copy_blocks, 256, 0, stream>>>(hb, NH4, stats);

        // z2 = z1 @ w2 + b2 -> zb ; BN + relu
        gemm_kernel<<<gemm_grid, 256, 0, stream>>>(hb, w2i, b2 + (size_t)i * HH, zb, N, HH);
        zero_kernel<<<2, 256, 0, stream>>>(stats, 2 * HH);
        bn_stats_kernel<<<cdiv(N, 128), HH, 0, stream>>>(zb, N, stats);
        bn_finalize_kernel<<<1, HH, 0, stream>>>(stats, bng + (size_t)i * HH, bnb + (size_t)i * HH, 1.f / N);
        bn_apply_relu_kernel<<<copy_blocks, 256, 0, stream>>>(zb, NH4, stats);

        float* tmp = hb; hb = zb; zb = tmp;
    }

    // global mean pool
    pool_kernel<<<B, HH, 0, stream>>>(hb, batch, N, pooled);

    // classifier
    dim3 cls_grid1(cdiv(B, 64), HH / 64);
    gemm_kernel<<<cls_grid1, 256, 0, stream>>>(pooled, cl1_w, cl1_b, zc, B, HH);
    zero_kernel<<<2, 256, 0, stream>>>(stats, 2 * HH);
    bn_stats_kernel<<<cdiv(B, 128), HH, 0, stream>>>(zc, B, stats);
    bn_finalize_kernel<<<1, HH, 0, stream>>>(stats, clg, clb, 1.f / B);
    bn_apply_relu_kernel<<<min(4096, cdiv(BH4, 256)), 256, 0, stream>>>(zc, BH4, stats);

    dim3 cls_grid2(cdiv(B, 64), T / 64);
    gemm_kernel<<<cls_grid2, 256, 0, stream>>>(zc, cl2_w, cl2_b, (float*)d_out, B, T);
}

// Round 5
// 1669.738 us; speedup vs baseline: 9.0083x; 1.4202x over previous
//
#include <hip/hip_runtime.h>
#include <hip/hip_bf16.h>
#include <stdint.h>

#define HH 256
#define BN_EPS 1e-5f
#define CHUNK 256

static inline int cdiv(int a, int b) { return (a + b - 1) / b; }

typedef __attribute__((ext_vector_type(8))) short bf16x8;
typedef __attribute__((ext_vector_type(4))) float f32x4;

__device__ __forceinline__ unsigned short f2bf(float f) {
    unsigned int u = __float_as_uint(f);
    u += 0x7fff + ((u >> 16) & 1);   // RNE
    return (unsigned short)(u >> 16);
}
__device__ __forceinline__ float bf2f(unsigned short h) {
    return __uint_as_float(((unsigned int)h) << 16);
}
// split x into hi+lo bf16
__device__ __forceinline__ void split_bf(float x, unsigned short& hi, unsigned short& lo) {
    hi = f2bf(x);
    lo = f2bf(x - bf2f(hi));
}

__device__ __forceinline__ void gload16(const void* g, void* lds) {
    __builtin_amdgcn_global_load_lds((const __attribute__((address_space(1))) unsigned int*)g,
                                     (__attribute__((address_space(3))) unsigned int*)lds, 16, 0, 0);
}

// ---------------- embed -> hi/lo planes ----------------
__global__ void embed_kernel(const float* __restrict__ xa, const float* __restrict__ xp,
                             const float* __restrict__ aw, const float* __restrict__ ab,
                             const float* __restrict__ pw, const float* __restrict__ pb,
                             unsigned short* __restrict__ hh, unsigned short* __restrict__ hl,
                             int N) {
    int n = blockIdx.x;
    int c = threadIdx.x;
    if (n >= N) return;
    float acc = ab[c] + pb[c];
#pragma unroll
    for (int k = 0; k < 9; ++k) acc += xa[n * 9 + k] * aw[k * HH + c];
#pragma unroll
    for (int k = 0; k < 8; ++k) acc += xp[n * 8 + k] * pw[k * HH + c];
    unsigned short hi, lo;
    split_bf(acc, hi, lo);
    hh[(size_t)n * HH + c] = hi;
    hl[(size_t)n * HH + c] = lo;
}

// ---------------- CSR build ----------------
__global__ void zero_int_kernel(int* __restrict__ p, int n) {
    int i = blockIdx.x * blockDim.x + threadIdx.x;
    if (i < n) p[i] = 0;
}

__global__ void hist_kernel(const int* __restrict__ ei, int* __restrict__ deg, int E) {
    int e = blockIdx.x * blockDim.x + threadIdx.x;
    if (e < E) atomicAdd(&deg[ei[(size_t)E + e]], 1);
}

__global__ void ps1_kernel(const int* __restrict__ deg, int* __restrict__ chunkSum, int N) {
    __shared__ int sm[CHUNK];
    int i = blockIdx.x * CHUNK + threadIdx.x;
    sm[threadIdx.x] = (i < N) ? deg[i] : 0;
    __syncthreads();
    for (int off = CHUNK / 2; off > 0; off >>= 1) {
        if (threadIdx.x < off) sm[threadIdx.x] += sm[threadIdx.x + off];
        __syncthreads();
    }
    if (threadIdx.x == 0) chunkSum[blockIdx.x] = sm[0];
}

__global__ void ps2_kernel(const int* __restrict__ chunkSum, int* __restrict__ chunkOff,
                           int nc, int* __restrict__ offs, int N, int E) {
    __shared__ int sm[CHUNK];
    int t = threadIdx.x;
    int own = (t < nc) ? chunkSum[t] : 0;
    sm[t] = own;
    for (int off = 1; off < CHUNK; off <<= 1) {
        __syncthreads();
        int v = (t >= off) ? sm[t - off] : 0;
        __syncthreads();
        sm[t] += v;
    }
    if (t < nc) chunkOff[t] = sm[t] - own;
    if (t == 0) offs[N] = E;
}

__global__ void ps3_kernel(const int* __restrict__ deg, const int* __restrict__ chunkOff,
                           int* __restrict__ offs, int* __restrict__ cursor, int N) {
    __shared__ int sm[CHUNK];
    int t = threadIdx.x;
    int i = blockIdx.x * CHUNK + t;
    int own = (i < N) ? deg[i] : 0;
    sm[t] = own;
    for (int off = 1; off < CHUNK; off <<= 1) {
        __syncthreads();
        int v = (t >= off) ? sm[t - off] : 0;
        __syncthreads();
        sm[t] += v;
    }
    if (i < N) {
        int o = chunkOff[blockIdx.x] + sm[t] - own;
        offs[i] = o;
        cursor[i] = o;
    }
}

__global__ void fill_kernel(const int* __restrict__ ei, int* __restrict__ cursor,
                            int* __restrict__ srcl, int E) {
    int e = blockIdx.x * blockDim.x + threadIdx.x;
    if (e >= E) return;
    int s = ei[e];
    int d = ei[(size_t)E + e];
    int pos = atomicAdd(&cursor[d], 1);
    srcl[pos] = s;
}

// ---------------- W transpose + split: Wt[n][k] = W[k][n] as hi/lo bf16 ----------------
__global__ void transpose_w_kernel(const float* __restrict__ W,
                                   unsigned short* __restrict__ Wth,
                                   unsigned short* __restrict__ Wtl) {
    __shared__ float tile[32][33];
    int mat = blockIdx.x >> 6, t = blockIdx.x & 63;
    int kt = (t >> 3) * 32, nt = (t & 7) * 32;
    const float* Wm = W + (size_t)mat * HH * HH;
    unsigned short* Wh = Wth + (size_t)mat * HH * HH;
    unsigned short* Wl = Wtl + (size_t)mat * HH * HH;
    int lx = threadIdx.x & 31, ly = threadIdx.x >> 5;   // 32 x 8
#pragma unroll
    for (int yy = 0; yy < 32; yy += 8)
        tile[ly + yy][lx] = Wm[(size_t)(kt + ly + yy) * HH + nt + lx];
    __syncthreads();
#pragma unroll
    for (int yy = 0; yy < 32; yy += 8) {
        float x = tile[lx][ly + yy];
        unsigned short hi, lo;
        split_bf(x, hi, lo);
        size_t idx = (size_t)(nt + ly + yy) * HH + kt + lx;
        Wh[idx] = hi;
        Wl[idx] = lo;
    }
}

// ---------------- aggregation on hi/lo planes: z[n] = h[n] + sum h[src_j] ----------------
__global__ __launch_bounds__(256) void aggregate_kernel(const unsigned short* __restrict__ hh,
                                                        const unsigned short* __restrict__ hl,
                                                        const int* __restrict__ offs,
                                                        const int* __restrict__ srcl,
                                                        unsigned short* __restrict__ zh,
                                                        unsigned short* __restrict__ zl,
                                                        int N) {
    int n = blockIdx.x * 4 + (threadIdx.x >> 6);
    int l = threadIdx.x & 63;
    if (n >= N) return;
    int c = l * 4;
    ushort4 svh = *(const ushort4*)&hh[(size_t)n * HH + c];
    ushort4 svl = *(const ushort4*)&hl[(size_t)n * HH + c];
    float a0 = bf2f(svh.x) + bf2f(svl.x);
    float a1 = bf2f(svh.y) + bf2f(svl.y);
    float a2 = bf2f(svh.z) + bf2f(svl.z);
    float a3 = bf2f(svh.w) + bf2f(svl.w);
    int s0 = offs[n], s1 = offs[n + 1];
    int j = s0;
    for (; j + 2 <= s1; j += 2) {
        int ra = srcl[j], rb = srcl[j + 1];
        ushort4 vah = *(const ushort4*)&hh[(size_t)ra * HH + c];
        ushort4 val = *(const ushort4*)&hl[(size_t)ra * HH + c];
        ushort4 vbh = *(const ushort4*)&hh[(size_t)rb * HH + c];
        ushort4 vbl = *(const ushort4*)&hl[(size_t)rb * HH + c];
        a0 += bf2f(vah.x) + bf2f(val.x) + bf2f(vbh.x) + bf2f(vbl.x);
        a1 += bf2f(vah.y) + bf2f(val.y) + bf2f(vbh.y) + bf2f(vbl.y);
        a2 += bf2f(vah.z) + bf2f(val.z) + bf2f(vbh.z) + bf2f(vbl.z);
        a3 += bf2f(vah.w) + bf2f(val.w) + bf2f(vbh.w) + bf2f(vbl.w);
    }
    if (j < s1) {
        int ra = srcl[j];
        ushort4 vah = *(const ushort4*)&hh[(size_t)ra * HH + c];
        ushort4 val = *(const ushort4*)&hl[(size_t)ra * HH + c];
        a0 += bf2f(vah.x) + bf2f(val.x);
        a1 += bf2f(vah.y) + bf2f(val.y);
        a2 += bf2f(vah.z) + bf2f(val.z);
        a3 += bf2f(vah.w) + bf2f(val.w);
    }
    ushort4 oh, ol;
    split_bf(a0, oh.x, ol.x);
    split_bf(a1, oh.y, ol.y);
    split_bf(a2, oh.z, ol.z);
    split_bf(a3, oh.w, ol.w);
    *(ushort4*)&zh[(size_t)n * HH + c] = oh;
    *(ushort4*)&zl[(size_t)n * HH + c] = ol;
}

// ---------------- split-bf16 MFMA GEMM (3-term): C = A @ W + bias ----------------
// A, W given as hi/lo bf16 planes; product uses ah*bh + ah*bl + al*bh (f32 MFMA accum).
// Tile 128x128, BK=64, 4 waves (2x2). LDS [128][64]bf16 x4 planes with 16B-granule
// XOR swizzle (g ^= row&7); staging pre-swizzles the GLOBAL source (rule #21).
// Fused BN partial stats into stats[0..511]; C written as hi/lo planes.
__global__ __launch_bounds__(256) void mfma_gemm_kernel(const unsigned short* __restrict__ Ah,
                                                        const unsigned short* __restrict__ Al,
                                                        const unsigned short* __restrict__ Wh,
                                                        const unsigned short* __restrict__ Wl,
                                                        const float* __restrict__ bias,
                                                        unsigned short* __restrict__ Ch,
                                                        unsigned short* __restrict__ Cl,
                                                        float* __restrict__ stats,
                                                        int M) {
    __shared__ short AsH[128 * 64];
    __shared__ short AsL[128 * 64];
    __shared__ short BsH[128 * 64];
    __shared__ short BsL[128 * 64];
    int tid = threadIdx.x;
    int w = tid >> 6, l = tid & 63;
    int wr = w >> 1, wc = w & 1;
    int row0 = blockIdx.x * 128;
    int col0 = blockIdx.y * 128;
    int g = (l & 7) ^ (l >> 3);      // pre-swizzled source granule
    int srow = w * 8 + (l >> 3);

    f32x4 acc[4][4] = {};

    const unsigned short* AhB = Ah + (size_t)row0 * HH;
    const unsigned short* AlB = Al + (size_t)row0 * HH;
    const unsigned short* WhB = Wh + (size_t)col0 * HH;
    const unsigned short* WlB = Wl + (size_t)col0 * HH;

    for (int k0 = 0; k0 < 256; k0 += 64) {
#pragma unroll
        for (int r = 0; r < 4; ++r) {
            int row = r * 32 + srow;
            size_t go = (size_t)row * HH + k0 + g * 8;
            int lo = (r * 32 + w * 8) * 64;
            gload16(AhB + go, &AsH[lo]);
            gload16(AlB + go, &AsL[lo]);
            gload16(WhB + go, &BsH[lo]);
            gload16(WlB + go, &BsL[lo]);
        }
        __syncthreads();
#pragma unroll
        for (int kh = 0; kh < 2; ++kh) {
            bf16x8 ah[4], al[4], bh[4], bl[4];
#pragma unroll
            for (int m = 0; m < 4; ++m) {
                int rr = wr * 64 + m * 16 + (l & 15);
                int gs = (kh * 4 + (l >> 4)) ^ (rr & 7);
                ah[m] = *(const bf16x8*)&AsH[rr * 64 + gs * 8];
                al[m] = *(const bf16x8*)&AsL[rr * 64 + gs * 8];
            }
#pragma unroll
            for (int n = 0; n < 4; ++n) {
                int rr = wc * 64 + n * 16 + (l & 15);
                int gs = (kh * 4 + (l >> 4)) ^ (rr & 7);
                bh[n] = *(const bf16x8*)&BsH[rr * 64 + gs * 8];
                bl[n] = *(const bf16x8*)&BsL[rr * 64 + gs * 8];
            }
#pragma unroll
            for (int m = 0; m < 4; ++m)
#pragma unroll
                for (int n = 0; n < 4; ++n) {
                    acc[m][n] = __builtin_amdgcn_mfma_f32_16x16x32_bf16(ah[m], bh[n], acc[m][n], 0, 0, 0);
                    acc[m][n] = __builtin_amdgcn_mfma_f32_16x16x32_bf16(ah[m], bl[n], acc[m][n], 0, 0, 0);
                    acc[m][n] = __builtin_amdgcn_mfma_f32_16x16x32_bf16(al[m], bh[n], acc[m][n], 0, 0, 0);
                }
        }
        __syncthreads();
    }

    // epilogue: bias, hi/lo store, fused BN partial stats
    int mvalid = M - row0;
#pragma unroll
    for (int n = 0; n < 4; ++n) {
        int col = col0 + wc * 64 + n * 16 + (l & 15);
        float bv = bias[col];
        float s = 0.f, s2 = 0.f;
#pragma unroll
        for (int m = 0; m < 4; ++m) {
            int rb = wr * 64 + m * 16 + (l >> 4) * 4;
#pragma unroll
            for (int r = 0; r < 4; ++r) {
                if (rb + r < mvalid) {
                    float v = acc[m][n][r] + bv;
                    size_t idx = (size_t)(row0 + rb + r) * HH + col;
                    unsigned short hi, lo;
                    split_bf(v, hi, lo);
                    Ch[idx] = hi;
                    Cl[idx] = lo;
                    s += v;
                    s2 += v * v;
                }
            }
        }
        s += __shfl_xor(s, 16);   s += __shfl_xor(s, 32);
        s2 += __shfl_xor(s2, 16); s2 += __shfl_xor(s2, 32);
        if ((l >> 4) == 0) {
            atomicAdd(&stats[col], s);
            atomicAdd(&stats[HH + col], s2);
        }
    }
}

// ---------------- BN helpers ----------------
__global__ void zero_kernel(float* __restrict__ p, int n) {
    int i = blockIdx.x * blockDim.x + threadIdx.x;
    if (i < n) p[i] = 0.f;
}

__global__ void bn_stats_kernel(const float* __restrict__ X, int M, float* __restrict__ stats) {
    int c = threadIdx.x;
    int r0 = blockIdx.x * 128;
    int r1 = min(r0 + 128, M);
    float s = 0.f, s2 = 0.f;
    for (int r = r0; r < r1; ++r) {
        float v = X[(size_t)r * HH + c];
        s += v;
        s2 += v * v;
    }
    atomicAdd(&stats[c], s);
    atomicAdd(&stats[HH + c], s2);
}

__global__ void bn_finalize_kernel(float* __restrict__ stats, const float* __restrict__ g,
                                   const float* __restrict__ b, float invM) {
    int c = threadIdx.x;
    float mu = stats[c] * invM;
    float var = stats[HH + c] * invM - mu * mu;
    float rstd = rsqrtf(var + BN_EPS);
    float sc = rstd * g[c];
    stats[2 * HH + c] = sc;
    stats[3 * HH + c] = b[c] - mu * sc;
}

// hi/lo in-place: x = relu(x*sc + sh), 8 elems/thread
__global__ void bn_apply_relu2_kernel(unsigned short* __restrict__ Xh,
                                      unsigned short* __restrict__ Xl, int n8,
                                      const float* __restrict__ stats) {
    int i = blockIdx.x * blockDim.x + threadIdx.x;
    int stride = gridDim.x * blockDim.x;
    for (; i < n8; i += stride) {
        int c0 = (i & 31) * 8;
        uint4 rh = *(const uint4*)&Xh[(size_t)i * 8];
        uint4 rl = *(const uint4*)&Xl[(size_t)i * 8];
        unsigned short vh[8], vl[8], oh[8], ol[8];
        *(uint4*)vh = rh;
        *(uint4*)vl = rl;
#pragma unroll
        for (int t = 0; t < 8; ++t) {
            float x = bf2f(vh[t]) + bf2f(vl[t]);
            float y = fmaxf(x * stats[2 * HH + c0 + t] + stats[3 * HH + c0 + t], 0.f);
            split_bf(y, oh[t], ol[t]);
        }
        *(uint4*)&Xh[(size_t)i * 8] = *(uint4*)oh;
        *(uint4*)&Xl[(size_t)i * 8] = *(uint4*)ol;
    }
}

// classifier-only f32 in-place apply
__global__ void bn_apply_relu_kernel(float* __restrict__ X, int n4, const float* __restrict__ stats) {
    int i = blockIdx.x * blockDim.x + threadIdx.x;
    int stride = gridDim.x * blockDim.x;
    for (; i < n4; i += stride) {
        int c4 = (i & 63) * 4;
        float4 v = ((float4*)X)[i];
        float4 sc = *(const float4*)&stats[2 * HH + c4];
        float4 sh = *(const float4*)&stats[3 * HH + c4];
        v.x = fmaxf(v.x * sc.x + sh.x, 0.f);
        v.y = fmaxf(v.y * sc.y + sh.y, 0.f);
        v.z = fmaxf(v.z * sc.z + sh.z, 0.f);
        v.w = fmaxf(v.w * sc.w + sh.w, 0.f);
        ((float4*)X)[i] = v;
    }
}

// ---------------- f32 GEMM (classifier only) ----------------
__global__ __launch_bounds__(256) void gemm_kernel(const float* __restrict__ A,
                                                   const float* __restrict__ W,
                                                   const float* __restrict__ bias,
                                                   float* __restrict__ C,
                                                   int M, int ldw) {
    __shared__ float Asm[64][33];
    __shared__ float Wsm[32][64];
    int tid = threadIdx.x;
    int tx = tid & 15, ty = tid >> 4;
    int row0 = blockIdx.x * 64;
    int col0 = blockIdx.y * 64;
    float acc[4][4] = {};

    for (int k0 = 0; k0 < 256; k0 += 32) {
#pragma unroll
        for (int t = 0; t < 2; ++t) {
            int s = tid + t * 256;
            int m = s >> 3;
            int kq = (s & 7) * 4;
            float4 v = make_float4(0.f, 0.f, 0.f, 0.f);
            if (row0 + m < M) v = *(const float4*)&A[(size_t)(row0 + m) * 256 + k0 + kq];
            Asm[m][kq + 0] = v.x; Asm[m][kq + 1] = v.y; Asm[m][kq + 2] = v.z; Asm[m][kq + 3] = v.w;
        }
#pragma unroll
        for (int t = 0; t < 2; ++t) {
            int s = tid + t * 256;
            int kk = s >> 4;
            int cq = (s & 15) * 4;
            *(float4*)&Wsm[kk][cq] = *(const float4*)&W[(size_t)(k0 + kk) * ldw + col0 + cq];
        }
        __syncthreads();
#pragma unroll
        for (int kk = 0; kk < 32; ++kk) {
            float a0 = Asm[ty * 4 + 0][kk];
            float a1 = Asm[ty * 4 + 1][kk];
            float a2 = Asm[ty * 4 + 2][kk];
            float a3 = Asm[ty * 4 + 3][kk];
            float4 wv = *(const float4*)&Wsm[kk][tx * 4];
            acc[0][0] += a0 * wv.x; acc[0][1] += a0 * wv.y; acc[0][2] += a0 * wv.z; acc[0][3] += a0 * wv.w;
            acc[1][0] += a1 * wv.x; acc[1][1] += a1 * wv.y; acc[1][2] += a1 * wv.z; acc[1][3] += a1 * wv.w;
            acc[2][0] += a2 * wv.x; acc[2][1] += a2 * wv.y; acc[2][2] += a2 * wv.z; acc[2][3] += a2 * wv.w;
            acc[3][0] += a3 * wv.x; acc[3][1] += a3 * wv.y; acc[3][2] += a3 * wv.z; acc[3][3] += a3 * wv.w;
        }
        __syncthreads();
    }

    float4 bv = *(const float4*)&bias[col0 + tx * 4];
#pragma unroll
    for (int j = 0; j < 4; ++j) {
        int row = row0 + ty * 4 + j;
        if (row < M) {
            float4 o = make_float4(acc[j][0] + bv.x, acc[j][1] + bv.y,
                                   acc[j][2] + bv.z, acc[j][3] + bv.w);
            *(float4*)&C[(size_t)row * ldw + col0 + tx * 4] = o;
        }
    }
}

// ---------------- mean pool per graph (hi/lo in, f32 out) ----------------
__device__ __forceinline__ int lbound(const int* a, int n, int v) {
    int lo = 0, hi = n;
    while (lo < hi) {
        int mid = (lo + hi) >> 1;
        if (a[mid] < v) lo = mid + 1; else hi = mid;
    }
    return lo;
}

__global__ void pool_kernel(const unsigned short* __restrict__ Hh,
                            const unsigned short* __restrict__ Hl,
                            const int* __restrict__ batch,
                            int N, float* __restrict__ pooled) {
    int g = blockIdx.x;
    int c = threadIdx.x;
    int s = lbound(batch, N, g);
    int e = lbound(batch, N, g + 1);
    float acc = 0.f;
    for (int r = s; r < e; ++r)
        acc += bf2f(Hh[(size_t)r * HH + c]) + bf2f(Hl[(size_t)r * HH + c]);
    pooled[(size_t)g * HH + c] = acc / (float)max(e - s, 1);
}

// ---------------- launch ----------------
extern "C" void kernel_launch(void* const* d_in, const int* in_sizes, int n_in,
                              void* d_out, int out_size, void* d_ws, size_t ws_size,
                              hipStream_t stream) {
    const float* x_atom = (const float*)d_in[0];
    const float* x_pe   = (const float*)d_in[1];
    const int* ei       = (const int*)d_in[2];
    const int* batch    = (const int*)d_in[3];
    const float* ae_w = (const float*)d_in[4];
    const float* ae_b = (const float*)d_in[5];
    const float* pe_w = (const float*)d_in[6];
    const float* pe_b = (const float*)d_in[7];
    const float* w1  = (const float*)d_in[8];
    const float* b1  = (const float*)d_in[9];
    const float* g1  = (const float*)d_in[10];
    const float* be1 = (const float*)d_in[11];
    const float* w2  = (const float*)d_in[12];
    const float* b2  = (const float*)d_in[13];
    const float* bng = (const float*)d_in[14];
    const float* bnb = (const float*)d_in[15];
    const float* cl1_w = (const float*)d_in[16];
    const float* cl1_b = (const float*)d_in[17];
    const float* clg = (const float*)d_in[18];
    const float* clb = (const float*)d_in[19];
    const float* cl2_w = (const float*)d_in[20];
    const float* cl2_b = (const float*)d_in[21];

    const int N = in_sizes[3];
    const int E = in_sizes[2] / 2;
    const int T = in_sizes[21];
    const int B = out_size / T;
    const int Lnum = in_sizes[9] / HH;
    const int nc = cdiv(N, CHUNK);
    const int Npad = cdiv(N, 128) * 128;   // staging never reads past plane end
    const size_t P = (size_t)Npad * HH;    // plane elems

    unsigned short* Xh = (unsigned short*)d_ws;
    unsigned short* Xl = Xh + P;
    unsigned short* Yh = Xl + P;
    unsigned short* Yl = Yh + P;
    unsigned short* wt1h = Yl + P;                       // L*HH*HH each
    unsigned short* wt1l = wt1h + (size_t)Lnum * HH * HH;
    unsigned short* wt2h = wt1l + (size_t)Lnum * HH * HH;
    unsigned short* wt2l = wt2h + (size_t)Lnum * HH * HH;
    float* stats = (float*)(wt2l + (size_t)Lnum * HH * HH);
    float* pooled = stats + 4 * HH;
    float* zc = pooled + (size_t)B * HH;
    int* deg = (int*)(zc + (size_t)B * HH);
    int* offs = deg + N;
    int* cursor = offs + N + 1;
    int* chunkSum = cursor + N;
    int* chunkOff = chunkSum + 256;
    int* srcl = chunkOff + 256;

    const int n8 = N * (HH / 8);
    const int BH4 = B * (HH / 4);

    // ---- CSR build ----
    zero_int_kernel<<<cdiv(N, 256), 256, 0, stream>>>(deg, N);
    hist_kernel<<<cdiv(E, 256), 256, 0, stream>>>(ei, deg, E);
    ps1_kernel<<<nc, CHUNK, 0, stream>>>(deg, chunkSum, N);
    ps2_kernel<<<1, CHUNK, 0, stream>>>(chunkSum, chunkOff, nc, offs, N, E);
    ps3_kernel<<<nc, CHUNK, 0, stream>>>(deg, chunkOff, offs, cursor, N);
    fill_kernel<<<cdiv(E, 256), 256, 0, stream>>>(ei, cursor, srcl, E);

    // ---- weight transpose + split ----
    transpose_w_kernel<<<Lnum * 64, 256, 0, stream>>>(w1, wt1h, wt1l);
    transpose_w_kernel<<<Lnum * 64, 256, 0, stream>>>(w2, wt2h, wt2l);

    // ---- embed ----
    embed_kernel<<<N, HH, 0, stream>>>(x_atom, x_pe, ae_w, ae_b, pe_w, pe_b, Xh, Xl, N);

    dim3 mf_grid(cdiv(N, 128), 2);
    int apply_blocks = min(2048, cdiv(n8, 256));

    for (int i = 0; i < Lnum; ++i) {
        // z = h + gather-sum : X -> Y
        aggregate_kernel<<<cdiv(N, 4), 256, 0, stream>>>(Xh, Xl, offs, srcl, Yh, Yl, N);

        // z1 = z @ w1 + b1 : Y -> X (h is dead) ; BN+relu in place
        zero_kernel<<<2, 256, 0, stream>>>(stats, 2 * HH);
        mfma_gemm_kernel<<<mf_grid, 256, 0, stream>>>(Yh, Yl,
                                                      wt1h + (size_t)i * HH * HH, wt1l + (size_t)i * HH * HH,
                                                      b1 + (size_t)i * HH, Xh, Xl, stats, N);
        bn_finalize_kernel<<<1, HH, 0, stream>>>(stats, g1 + (size_t)i * HH, be1 + (size_t)i * HH, 1.f / N);
        bn_apply_relu2_kernel<<<apply_blocks, 256, 0, stream>>>(Xh, Xl, n8, stats);

        // z2 = a1 @ w2 + b2 : X -> Y (z is dead) ; BN+relu in place -> new h in Y
        zero_kernel<<<2, 256, 0, stream>>>(stats, 2 * HH);
        mfma_gemm_kernel<<<mf_grid, 256, 0, stream>>>(Xh, Xl,
                                                      wt2h + (size_t)i * HH * HH, wt2l + (size_t)i * HH * HH,
                                                      b2 + (size_t)i * HH, Yh, Yl, stats, N);
        bn_finalize_kernel<<<1, HH, 0, stream>>>(stats, bng + (size_t)i * HH, bnb + (size_t)i * HH, 1.f / N);
        bn_apply_relu2_kernel<<<apply_blocks, 256, 0, stream>>>(Yh, Yl, n8, stats);

        // swap: new h in Y
        unsigned short* t;
        t = Xh; Xh = Yh; Yh = t;
        t = Xl; Xl = Yl; Yl = t;
    }

    // ---- global mean pool ----
    pool_kernel<<<B, HH, 0, stream>>>(Xh, Xl, batch, N, pooled);

    // ---- classifier (f32 path) ----
    dim3 cls_grid1(cdiv(B, 64), HH / 64);
    gemm_kernel<<<cls_grid1, 256, 0, stream>>>(pooled, cl1_w, cl1_b, zc, B, HH);
    zero_kernel<<<2, 256, 0, stream>>>(stats, 2 * HH);
    bn_stats_kernel<<<cdiv(B, 128), HH, 0, stream>>>(zc, B, stats);
    bn_finalize_kernel<<<1, HH, 0, stream>>>(stats, clg, clb, 1.f / B);
    bn_apply_relu_kernel<<<min(2048, cdiv(BH4, 256)), 256, 0, stream>>>(zc, BH4, stats);

    dim3 cls_grid2(cdiv(B, 64), T / 64);
    gemm_kernel<<<cls_grid2, 256, 0, stream>>>(zc, cl2_w, cl2_b, (float*)d_out, B, T);
}

// Round 6
// 1617.400 us; speedup vs baseline: 9.2998x; 1.0324x over previous
//
#include <hip/hip_runtime.h>
#include <hip/hip_bf16.h>
#include <stdint.h>

#define HH 256
#define BN_EPS 1e-5f
#define CHUNK 256
#define NSLOT 12   // per-BN stats slots: layer i -> 2i (inner), 2i+1 (outer); classifier -> 10

static inline int cdiv(int a, int b) { return (a + b - 1) / b; }

typedef __attribute__((ext_vector_type(8))) short bf16x8;
typedef __attribute__((ext_vector_type(4))) float f32x4;

__device__ __forceinline__ unsigned short f2bf(float f) {
    unsigned int u = __float_as_uint(f);
    u += 0x7fff + ((u >> 16) & 1);   // RNE
    return (unsigned short)(u >> 16);
}
__device__ __forceinline__ float bf2f(unsigned short h) {
    return __uint_as_float(((unsigned int)h) << 16);
}
__device__ __forceinline__ void split_bf(float x, unsigned short& hi, unsigned short& lo) {
    hi = f2bf(x);
    lo = f2bf(x - bf2f(hi));
}

__device__ __forceinline__ void gload16(const void* g, void* lds) {
    __builtin_amdgcn_global_load_lds((const __attribute__((address_space(1))) unsigned int*)g,
                                     (__attribute__((address_space(3))) unsigned int*)lds, 16, 0, 0);
}

// ---------------- embed -> hi/lo planes ----------------
__global__ void embed_kernel(const float* __restrict__ xa, const float* __restrict__ xp,
                             const float* __restrict__ aw, const float* __restrict__ ab,
                             const float* __restrict__ pw, const float* __restrict__ pb,
                             unsigned short* __restrict__ hh, unsigned short* __restrict__ hl,
                             int N) {
    int n = blockIdx.x;
    int c = threadIdx.x;
    if (n >= N) return;
    float acc = ab[c] + pb[c];
#pragma unroll
    for (int k = 0; k < 9; ++k) acc += xa[n * 9 + k] * aw[k * HH + c];
#pragma unroll
    for (int k = 0; k < 8; ++k) acc += xp[n * 8 + k] * pw[k * HH + c];
    unsigned short hi, lo;
    split_bf(acc, hi, lo);
    hh[(size_t)n * HH + c] = hi;
    hl[(size_t)n * HH + c] = lo;
}

// ---------------- CSR build ----------------
__global__ void zero_int_kernel(int* __restrict__ p, int n) {
    int i = blockIdx.x * blockDim.x + threadIdx.x;
    if (i < n) p[i] = 0;
}

__global__ void hist_kernel(const int* __restrict__ ei, int* __restrict__ deg, int E) {
    int e = blockIdx.x * blockDim.x + threadIdx.x;
    if (e < E) atomicAdd(&deg[ei[(size_t)E + e]], 1);
}

__global__ void ps1_kernel(const int* __restrict__ deg, int* __restrict__ chunkSum, int N) {
    __shared__ int sm[CHUNK];
    int i = blockIdx.x * CHUNK + threadIdx.x;
    sm[threadIdx.x] = (i < N) ? deg[i] : 0;
    __syncthreads();
    for (int off = CHUNK / 2; off > 0; off >>= 1) {
        if (threadIdx.x < off) sm[threadIdx.x] += sm[threadIdx.x + off];
        __syncthreads();
    }
    if (threadIdx.x == 0) chunkSum[blockIdx.x] = sm[0];
}

__global__ void ps2_kernel(const int* __restrict__ chunkSum, int* __restrict__ chunkOff,
                           int nc, int* __restrict__ offs, int N, int E) {
    __shared__ int sm[CHUNK];
    int t = threadIdx.x;
    int own = (t < nc) ? chunkSum[t] : 0;
    sm[t] = own;
    for (int off = 1; off < CHUNK; off <<= 1) {
        __syncthreads();
        int v = (t >= off) ? sm[t - off] : 0;
        __syncthreads();
        sm[t] += v;
    }
    if (t < nc) chunkOff[t] = sm[t] - own;
    if (t == 0) offs[N] = E;
}

__global__ void ps3_kernel(const int* __restrict__ deg, const int* __restrict__ chunkOff,
                           int* __restrict__ offs, int* __restrict__ cursor, int N) {
    __shared__ int sm[CHUNK];
    int t = threadIdx.x;
    int i = blockIdx.x * CHUNK + t;
    int own = (i < N) ? deg[i] : 0;
    sm[t] = own;
    for (int off = 1; off < CHUNK; off <<= 1) {
        __syncthreads();
        int v = (t >= off) ? sm[t - off] : 0;
        __syncthreads();
        sm[t] += v;
    }
    if (i < N) {
        int o = chunkOff[blockIdx.x] + sm[t] - own;
        offs[i] = o;
        cursor[i] = o;
    }
}

__global__ void fill_kernel(const int* __restrict__ ei, int* __restrict__ cursor,
                            int* __restrict__ srcl, int E) {
    int e = blockIdx.x * blockDim.x + threadIdx.x;
    if (e >= E) return;
    int s = ei[e];
    int d = ei[(size_t)E + e];
    int pos = atomicAdd(&cursor[d], 1);
    srcl[pos] = s;
}

// ---------------- W transpose + split ----------------
__global__ void transpose_w_kernel(const float* __restrict__ W,
                                   unsigned short* __restrict__ Wth,
                                   unsigned short* __restrict__ Wtl) {
    __shared__ float tile[32][33];
    int mat = blockIdx.x >> 6, t = blockIdx.x & 63;
    int kt = (t >> 3) * 32, nt = (t & 7) * 32;
    const float* Wm = W + (size_t)mat * HH * HH;
    unsigned short* Wh = Wth + (size_t)mat * HH * HH;
    unsigned short* Wl = Wtl + (size_t)mat * HH * HH;
    int lx = threadIdx.x & 31, ly = threadIdx.x >> 5;
#pragma unroll
    for (int yy = 0; yy < 32; yy += 8)
        tile[ly + yy][lx] = Wm[(size_t)(kt + ly + yy) * HH + nt + lx];
    __syncthreads();
#pragma unroll
    for (int yy = 0; yy < 32; yy += 8) {
        float x = tile[lx][ly + yy];
        unsigned short hi, lo;
        split_bf(x, hi, lo);
        size_t idx = (size_t)(nt + ly + yy) * HH + kt + lx;
        Wh[idx] = hi;
        Wl[idx] = lo;
    }
}

// ---------------- stats init: zero sum regions of all slots ----------------
__global__ void init_stats_kernel(float* __restrict__ stats) {
    int i = blockIdx.x * blockDim.x + threadIdx.x;
    int slot = i >> 9;               // 512 sums per slot
    if (slot < NSLOT) stats[(size_t)slot * 4 * HH + (i & 511)] = 0.f;
}

// ---------------- fused aggregation: z[n] = t(x[n]) + sum t(x[src_j]) ----------------
// t(x) = relu(x*sc+sh) when stats != null (x = raw GEMM2 output), else identity (embed h).
__global__ __launch_bounds__(256) void aggregate_fused_kernel(
        const unsigned short* __restrict__ hh, const unsigned short* __restrict__ hl,
        const int* __restrict__ offs, const int* __restrict__ srcl,
        const float* __restrict__ stats,
        unsigned short* __restrict__ zh, unsigned short* __restrict__ zl, int N) {
    int n = blockIdx.x * 4 + (threadIdx.x >> 6);
    int l = threadIdx.x & 63;
    if (n >= N) return;
    int c = l * 4;
    const bool apply = (stats != nullptr);
    float4 sc = make_float4(1.f, 1.f, 1.f, 1.f), sh = make_float4(0.f, 0.f, 0.f, 0.f);
    if (apply) {
        sc = *(const float4*)&stats[2 * HH + c];
        sh = *(const float4*)&stats[3 * HH + c];
    }

#define LOADT(row, r0, r1, r2, r3)                                             \
    {                                                                          \
        ushort4 vh_ = *(const ushort4*)&hh[(size_t)(row) * HH + c];            \
        ushort4 vl_ = *(const ushort4*)&hl[(size_t)(row) * HH + c];            \
        r0 = bf2f(vh_.x) + bf2f(vl_.x);                                        \
        r1 = bf2f(vh_.y) + bf2f(vl_.y);                                        \
        r2 = bf2f(vh_.z) + bf2f(vl_.z);                                        \
        r3 = bf2f(vh_.w) + bf2f(vl_.w);                                        \
        if (apply) {                                                           \
            r0 = fmaxf(r0 * sc.x + sh.x, 0.f);                                 \
            r1 = fmaxf(r1 * sc.y + sh.y, 0.f);                                 \
            r2 = fmaxf(r2 * sc.z + sh.z, 0.f);                                 \
            r3 = fmaxf(r3 * sc.w + sh.w, 0.f);                                 \
        }                                                                      \
    }

    float a0, a1, a2, a3;
    LOADT(n, a0, a1, a2, a3);
    int s0 = offs[n], s1 = offs[n + 1];
    int j = s0;
    for (; j + 2 <= s1; j += 2) {
        int ra = srcl[j], rb = srcl[j + 1];
        float t0, t1, t2, t3, u0, u1, u2, u3;
        LOADT(ra, t0, t1, t2, t3);
        LOADT(rb, u0, u1, u2, u3);
        a0 += t0 + u0; a1 += t1 + u1; a2 += t2 + u2; a3 += t3 + u3;
    }
    if (j < s1) {
        float t0, t1, t2, t3;
        LOADT(srcl[j], t0, t1, t2, t3);
        a0 += t0; a1 += t1; a2 += t2; a3 += t3;
    }
#undef LOADT
    ushort4 oh, ol;
    split_bf(a0, oh.x, ol.x);
    split_bf(a1, oh.y, ol.y);
    split_bf(a2, oh.z, ol.z);
    split_bf(a3, oh.w, ol.w);
    *(ushort4*)&zh[(size_t)n * HH + c] = oh;
    *(ushort4*)&zl[(size_t)n * HH + c] = ol;
}

// ---------------- split-bf16 MFMA GEMM (3-term) + fused BN partial stats ----------------
__global__ __launch_bounds__(256) void mfma_gemm_kernel(const unsigned short* __restrict__ Ah,
                                                        const unsigned short* __restrict__ Al,
                                                        const unsigned short* __restrict__ Wh,
                                                        const unsigned short* __restrict__ Wl,
                                                        const float* __restrict__ bias,
                                                        unsigned short* __restrict__ Ch,
                                                        unsigned short* __restrict__ Cl,
                                                        float* __restrict__ stats,
                                                        int M) {
    __shared__ short AsH[128 * 64];
    __shared__ short AsL[128 * 64];
    __shared__ short BsH[128 * 64];
    __shared__ short BsL[128 * 64];
    int tid = threadIdx.x;
    int w = tid >> 6, l = tid & 63;
    int wr = w >> 1, wc = w & 1;
    int row0 = blockIdx.x * 128;
    int col0 = blockIdx.y * 128;
    int g = (l & 7) ^ (l >> 3);      // pre-swizzled source granule
    int srow = w * 8 + (l >> 3);

    f32x4 acc[4][4] = {};

    const unsigned short* AhB = Ah + (size_t)row0 * HH;
    const unsigned short* AlB = Al + (size_t)row0 * HH;
    const unsigned short* WhB = Wh + (size_t)col0 * HH;
    const unsigned short* WlB = Wl + (size_t)col0 * HH;

    for (int k0 = 0; k0 < 256; k0 += 64) {
#pragma unroll
        for (int r = 0; r < 4; ++r) {
            int row = r * 32 + srow;
            size_t go = (size_t)row * HH + k0 + g * 8;
            int lo = (r * 32 + w * 8) * 64;
            gload16(AhB + go, &AsH[lo]);
            gload16(AlB + go, &AsL[lo]);
            gload16(WhB + go, &BsH[lo]);
            gload16(WlB + go, &BsL[lo]);
        }
        __syncthreads();
#pragma unroll
        for (int kh = 0; kh < 2; ++kh) {
            bf16x8 ah[4], al[4], bh[4], bl[4];
#pragma unroll
            for (int m = 0; m < 4; ++m) {
                int rr = wr * 64 + m * 16 + (l & 15);
                int gs = (kh * 4 + (l >> 4)) ^ (rr & 7);
                ah[m] = *(const bf16x8*)&AsH[rr * 64 + gs * 8];
                al[m] = *(const bf16x8*)&AsL[rr * 64 + gs * 8];
            }
#pragma unroll
            for (int n = 0; n < 4; ++n) {
                int rr = wc * 64 + n * 16 + (l & 15);
                int gs = (kh * 4 + (l >> 4)) ^ (rr & 7);
                bh[n] = *(const bf16x8*)&BsH[rr * 64 + gs * 8];
                bl[n] = *(const bf16x8*)&BsL[rr * 64 + gs * 8];
            }
#pragma unroll
            for (int m = 0; m < 4; ++m)
#pragma unroll
                for (int n = 0; n < 4; ++n) {
                    acc[m][n] = __builtin_amdgcn_mfma_f32_16x16x32_bf16(ah[m], bh[n], acc[m][n], 0, 0, 0);
                    acc[m][n] = __builtin_amdgcn_mfma_f32_16x16x32_bf16(ah[m], bl[n], acc[m][n], 0, 0, 0);
                    acc[m][n] = __builtin_amdgcn_mfma_f32_16x16x32_bf16(al[m], bh[n], acc[m][n], 0, 0, 0);
                }
        }
        __syncthreads();
    }

    int mvalid = M - row0;
#pragma unroll
    for (int n = 0; n < 4; ++n) {
        int col = col0 + wc * 64 + n * 16 + (l & 15);
        float bv = bias[col];
        float s = 0.f, s2 = 0.f;
#pragma unroll
        for (int m = 0; m < 4; ++m) {
            int rb = wr * 64 + m * 16 + (l >> 4) * 4;
#pragma unroll
            for (int r = 0; r < 4; ++r) {
                if (rb + r < mvalid) {
                    float v = acc[m][n][r] + bv;
                    size_t idx = (size_t)(row0 + rb + r) * HH + col;
                    unsigned short hi, lo;
                    split_bf(v, hi, lo);
                    Ch[idx] = hi;
                    Cl[idx] = lo;
                    s += v;
                    s2 += v * v;
                }
            }
        }
        s += __shfl_xor(s, 16);   s += __shfl_xor(s, 32);
        s2 += __shfl_xor(s2, 16); s2 += __shfl_xor(s2, 32);
        if ((l >> 4) == 0) {
            atomicAdd(&stats[col], s);
            atomicAdd(&stats[HH + col], s2);
        }
    }
}

// ---------------- BN helpers ----------------
__global__ void bn_stats_kernel(const float* __restrict__ X, int M, float* __restrict__ stats) {
    int c = threadIdx.x;
    int r0 = blockIdx.x * 128;
    int r1 = min(r0 + 128, M);
    float s = 0.f, s2 = 0.f;
    for (int r = r0; r < r1; ++r) {
        float v = X[(size_t)r * HH + c];
        s += v;
        s2 += v * v;
    }
    atomicAdd(&stats[c], s);
    atomicAdd(&stats[HH + c], s2);
}

__global__ void bn_finalize_kernel(float* __restrict__ stats, const float* __restrict__ g,
                                   const float* __restrict__ b, float invM) {
    int c = threadIdx.x;
    float mu = stats[c] * invM;
    float var = stats[HH + c] * invM - mu * mu;
    float rstd = rsqrtf(var + BN_EPS);
    float sc = rstd * g[c];
    stats[2 * HH + c] = sc;
    stats[3 * HH + c] = b[c] - mu * sc;
}

// hi/lo in-place: x = relu(x*sc + sh)  (used only for z1, GEMM2's A input)
__global__ void bn_apply_relu2_kernel(unsigned short* __restrict__ Xh,
                                      unsigned short* __restrict__ Xl, int n8,
                                      const float* __restrict__ stats) {
    int i = blockIdx.x * blockDim.x + threadIdx.x;
    int stride = gridDim.x * blockDim.x;
    for (; i < n8; i += stride) {
        int c0 = (i & 31) * 8;
        uint4 rh = *(const uint4*)&Xh[(size_t)i * 8];
        uint4 rl = *(const uint4*)&Xl[(size_t)i * 8];
        unsigned short vh[8], vl[8], oh[8], ol[8];
        *(uint4*)vh = rh;
        *(uint4*)vl = rl;
#pragma unroll
        for (int t = 0; t < 8; ++t) {
            float x = bf2f(vh[t]) + bf2f(vl[t]);
            float y = fmaxf(x * stats[2 * HH + c0 + t] + stats[3 * HH + c0 + t], 0.f);
            split_bf(y, oh[t], ol[t]);
        }
        *(uint4*)&Xh[(size_t)i * 8] = *(uint4*)oh;
        *(uint4*)&Xl[(size_t)i * 8] = *(uint4*)ol;
    }
}

// classifier-only f32 in-place apply
__global__ void bn_apply_relu_kernel(float* __restrict__ X, int n4, const float* __restrict__ stats) {
    int i = blockIdx.x * blockDim.x + threadIdx.x;
    int stride = gridDim.x * blockDim.x;
    for (; i < n4; i += stride) {
        int c4 = (i & 63) * 4;
        float4 v = ((float4*)X)[i];
        float4 sc = *(const float4*)&stats[2 * HH + c4];
        float4 sh = *(const float4*)&stats[3 * HH + c4];
        v.x = fmaxf(v.x * sc.x + sh.x, 0.f);
        v.y = fmaxf(v.y * sc.y + sh.y, 0.f);
        v.z = fmaxf(v.z * sc.z + sh.z, 0.f);
        v.w = fmaxf(v.w * sc.w + sh.w, 0.f);
        ((float4*)X)[i] = v;
    }
}

// ---------------- f32 GEMM (classifier only) ----------------
__global__ __launch_bounds__(256) void gemm_kernel(const float* __restrict__ A,
                                                   const float* __restrict__ W,
                                                   const float* __restrict__ bias,
                                                   float* __restrict__ C,
                                                   int M, int ldw) {
    __shared__ float Asm[64][33];
    __shared__ float Wsm[32][64];
    int tid = threadIdx.x;
    int tx = tid & 15, ty = tid >> 4;
    int row0 = blockIdx.x * 64;
    int col0 = blockIdx.y * 64;
    float acc[4][4] = {};

    for (int k0 = 0; k0 < 256; k0 += 32) {
#pragma unroll
        for (int t = 0; t < 2; ++t) {
            int s = tid + t * 256;
            int m = s >> 3;
            int kq = (s & 7) * 4;
            float4 v = make_float4(0.f, 0.f, 0.f, 0.f);
            if (row0 + m < M) v = *(const float4*)&A[(size_t)(row0 + m) * 256 + k0 + kq];
            Asm[m][kq + 0] = v.x; Asm[m][kq + 1] = v.y; Asm[m][kq + 2] = v.z; Asm[m][kq + 3] = v.w;
        }
#pragma unroll
        for (int t = 0; t < 2; ++t) {
            int s = tid + t * 256;
            int kk = s >> 4;
            int cq = (s & 15) * 4;
            *(float4*)&Wsm[kk][cq] = *(const float4*)&W[(size_t)(k0 + kk) * ldw + col0 + cq];
        }
        __syncthreads();
#pragma unroll
        for (int kk = 0; kk < 32; ++kk) {
            float a0 = Asm[ty * 4 + 0][kk];
            float a1 = Asm[ty * 4 + 1][kk];
            float a2 = Asm[ty * 4 + 2][kk];
            float a3 = Asm[ty * 4 + 3][kk];
            float4 wv = *(const float4*)&Wsm[kk][tx * 4];
            acc[0][0] += a0 * wv.x; acc[0][1] += a0 * wv.y; acc[0][2] += a0 * wv.z; acc[0][3] += a0 * wv.w;
            acc[1][0] += a1 * wv.x; acc[1][1] += a1 * wv.y; acc[1][2] += a1 * wv.z; acc[1][3] += a1 * wv.w;
            acc[2][0] += a2 * wv.x; acc[2][1] += a2 * wv.y; acc[2][2] += a2 * wv.z; acc[2][3] += a2 * wv.w;
            acc[3][0] += a3 * wv.x; acc[3][1] += a3 * wv.y; acc[3][2] += a3 * wv.z; acc[3][3] += a3 * wv.w;
        }
        __syncthreads();
    }

    float4 bv = *(const float4*)&bias[col0 + tx * 4];
#pragma unroll
    for (int j = 0; j < 4; ++j) {
        int row = row0 + ty * 4 + j;
        if (row < M) {
            float4 o = make_float4(acc[j][0] + bv.x, acc[j][1] + bv.y,
                                   acc[j][2] + bv.z, acc[j][3] + bv.w);
            *(float4*)&C[(size_t)row * ldw + col0 + tx * 4] = o;
        }
    }
}

// ---------------- fused mean pool: pooled = mean relu(bn(z2_last)) ----------------
__device__ __forceinline__ int lbound(const int* a, int n, int v) {
    int lo = 0, hi = n;
    while (lo < hi) {
        int mid = (lo + hi) >> 1;
        if (a[mid] < v) lo = mid + 1; else hi = mid;
    }
    return lo;
}

__global__ void pool_fused_kernel(const unsigned short* __restrict__ Hh,
                                  const unsigned short* __restrict__ Hl,
                                  const int* __restrict__ batch,
                                  const float* __restrict__ stats,
                                  int N, float* __restrict__ pooled) {
    int g = blockIdx.x;
    int c = threadIdx.x;
    int s = lbound(batch, N, g);
    int e = lbound(batch, N, g + 1);
    float sc = stats[2 * HH + c];
    float sh = stats[3 * HH + c];
    float acc = 0.f;
    for (int r = s; r < e; ++r) {
        float x = bf2f(Hh[(size_t)r * HH + c]) + bf2f(Hl[(size_t)r * HH + c]);
        acc += fmaxf(x * sc + sh, 0.f);
    }
    pooled[(size_t)g * HH + c] = acc / (float)max(e - s, 1);
}

// ---------------- launch ----------------
extern "C" void kernel_launch(void* const* d_in, const int* in_sizes, int n_in,
                              void* d_out, int out_size, void* d_ws, size_t ws_size,
                              hipStream_t stream) {
    const float* x_atom = (const float*)d_in[0];
    const float* x_pe   = (const float*)d_in[1];
    const int* ei       = (const int*)d_in[2];
    const int* batch    = (const int*)d_in[3];
    const float* ae_w = (const float*)d_in[4];
    const float* ae_b = (const float*)d_in[5];
    const float* pe_w = (const float*)d_in[6];
    const float* pe_b = (const float*)d_in[7];
    const float* w1  = (const float*)d_in[8];
    const float* b1  = (const float*)d_in[9];
    const float* g1  = (const float*)d_in[10];
    const float* be1 = (const float*)d_in[11];
    const float* w2  = (const float*)d_in[12];
    const float* b2  = (const float*)d_in[13];
    const float* bng = (const float*)d_in[14];
    const float* bnb = (const float*)d_in[15];
    const float* cl1_w = (const float*)d_in[16];
    const float* cl1_b = (const float*)d_in[17];
    const float* clg = (const float*)d_in[18];
    const float* clb = (const float*)d_in[19];
    const float* cl2_w = (const float*)d_in[20];
    const float* cl2_b = (const float*)d_in[21];

    const int N = in_sizes[3];
    const int E = in_sizes[2] / 2;
    const int T = in_sizes[21];
    const int B = out_size / T;
    const int Lnum = in_sizes[9] / HH;
    const int nc = cdiv(N, CHUNK);
    const int Npad = cdiv(N, 128) * 128;
    const size_t P = (size_t)Npad * HH;

    unsigned short* Xh = (unsigned short*)d_ws;
    unsigned short* Xl = Xh + P;
    unsigned short* Yh = Xl + P;
    unsigned short* Yl = Yh + P;
    unsigned short* wt1h = Yl + P;
    unsigned short* wt1l = wt1h + (size_t)Lnum * HH * HH;
    unsigned short* wt2h = wt1l + (size_t)Lnum * HH * HH;
    unsigned short* wt2l = wt2h + (size_t)Lnum * HH * HH;
    float* stats = (float*)(wt2l + (size_t)Lnum * HH * HH);   // NSLOT x 4*HH
    float* pooled = stats + (size_t)NSLOT * 4 * HH;
    float* zc = pooled + (size_t)B * HH;
    int* deg = (int*)(zc + (size_t)B * HH);
    int* offs = deg + N;
    int* cursor = offs + N + 1;
    int* chunkSum = cursor + N;
    int* chunkOff = chunkSum + 256;
    int* srcl = chunkOff + 256;

    const int n8 = N * (HH / 8);
    const int BH4 = B * (HH / 4);

    // ---- CSR build ----
    zero_int_kernel<<<cdiv(N, 256), 256, 0, stream>>>(deg, N);
    hist_kernel<<<cdiv(E, 256), 256, 0, stream>>>(ei, deg, E);
    ps1_kernel<<<nc, CHUNK, 0, stream>>>(deg, chunkSum, N);
    ps2_kernel<<<1, CHUNK, 0, stream>>>(chunkSum, chunkOff, nc, offs, N, E);
    ps3_kernel<<<nc, CHUNK, 0, stream>>>(deg, chunkOff, offs, cursor, N);
    fill_kernel<<<cdiv(E, 256), 256, 0, stream>>>(ei, cursor, srcl, E);

    // ---- weight transpose + split ----
    transpose_w_kernel<<<Lnum * 64, 256, 0, stream>>>(w1, wt1h, wt1l);
    transpose_w_kernel<<<Lnum * 64, 256, 0, stream>>>(w2, wt2h, wt2l);

    // ---- stats init (all slots, once) ----
    init_stats_kernel<<<cdiv(NSLOT * 512, 256), 256, 0, stream>>>(stats);

    // ---- embed ----
    embed_kernel<<<N, HH, 0, stream>>>(x_atom, x_pe, ae_w, ae_b, pe_w, pe_b, Xh, Xl, N);

    dim3 mf_grid(cdiv(N, 128), 2);
    int apply_blocks = min(2048, cdiv(n8, 256));

    // ping-pong: layer input (raw z2 planes, or embed h) alternates X,Y
    unsigned short *inh = Xh, *inl = Xl, *oth = Yh, *otl = Yl;

    for (int i = 0; i < Lnum; ++i) {
        float* slot1 = stats + (size_t)(2 * i) * 4 * HH;
        float* slot2 = stats + (size_t)(2 * i + 1) * 4 * HH;
        const float* aggStats = (i == 0) ? nullptr : stats + (size_t)(2 * i - 1) * 4 * HH;

        // z = t(in) + gather-sum t(in[src]) : in -> ot
        aggregate_fused_kernel<<<cdiv(N, 4), 256, 0, stream>>>(inh, inl, offs, srcl,
                                                               aggStats, oth, otl, N);

        // z1 = z @ w1 + b1 : ot -> in (in is dead) ; inner BN+relu in place
        mfma_gemm_kernel<<<mf_grid, 256, 0, stream>>>(oth, otl,
                                                      wt1h + (size_t)i * HH * HH, wt1l + (size_t)i * HH * HH,
                                                      b1 + (size_t)i * HH, inh, inl, slot1, N);
        bn_finalize_kernel<<<1, HH, 0, stream>>>(slot1, g1 + (size_t)i * HH, be1 + (size_t)i * HH, 1.f / N);
        bn_apply_relu2_kernel<<<apply_blocks, 256, 0, stream>>>(inh, inl, n8, slot1);

        // z2 = a1 @ w2 + b2 : in -> ot (raw; outer BN fused into next consumer)
        mfma_gemm_kernel<<<mf_grid, 256, 0, stream>>>(inh, inl,
                                                      wt2h + (size_t)i * HH * HH, wt2l + (size_t)i * HH * HH,
                                                      b2 + (size_t)i * HH, oth, otl, slot2, N);
        bn_finalize_kernel<<<1, HH, 0, stream>>>(slot2, bng + (size_t)i * HH, bnb + (size_t)i * HH, 1.f / N);

        // next layer input = ot (raw z2)
        unsigned short* t;
        t = inh; inh = oth; oth = t;
        t = inl; inl = otl; otl = t;
    }

    // ---- fused mean pool (applies last outer BN+relu) ----
    pool_fused_kernel<<<B, HH, 0, stream>>>(inh, inl, batch,
                                            stats + (size_t)(2 * Lnum - 1) * 4 * HH, N, pooled);

    // ---- classifier (f32 path, slot 10) ----
    float* slotC = stats + (size_t)10 * 4 * HH;
    dim3 cls_grid1(cdiv(B, 64), HH / 64);
    gemm_kernel<<<cls_grid1, 256, 0, stream>>>(pooled, cl1_w, cl1_b, zc, B, HH);
    bn_stats_kernel<<<cdiv(B, 128), HH, 0, stream>>>(zc, B, slotC);
    bn_finalize_kernel<<<1, HH, 0, stream>>>(slotC, clg, clb, 1.f / B);
    bn_apply_relu_kernel<<<min(2048, cdiv(BH4, 256)), 256, 0, stream>>>(zc, BH4, slotC);

    dim3 cls_grid2(cdiv(B, 64), T / 64);
    gemm_kernel<<<cls_grid2, 256, 0, stream>>>(zc, cl2_w, cl2_b, (float*)d_out, B, T);
}

// Round 7
// 1179.750 us; speedup vs baseline: 12.7497x; 1.3710x over previous
//
#include <hip/hip_runtime.h>
#include <hip/hip_bf16.h>
#include <stdint.h>

#define HH 256
#define BN_EPS 1e-5f
#define CHUNK 256
#define NSLOT 12   // stats slots: layer i -> 2i (inner), 2i+1 (outer); classifier -> 10

static inline int cdiv(int a, int b) { return (a + b - 1) / b; }

typedef _Float16 f16x8 __attribute__((ext_vector_type(8)));
typedef __attribute__((ext_vector_type(4))) float f32x4;

__device__ __forceinline__ unsigned short f2h(float f) {
    _Float16 h = (_Float16)f;            // v_cvt_f16_f32, RNE
    unsigned short u;
    __builtin_memcpy(&u, &h, 2);
    return u;
}
__device__ __forceinline__ float h2f(unsigned short u) {
    _Float16 h;
    __builtin_memcpy(&h, &u, 2);
    return (float)h;
}

__device__ __forceinline__ void gload16(const void* g, void* lds) {
    __builtin_amdgcn_global_load_lds((const __attribute__((address_space(1))) unsigned int*)g,
                                     (__attribute__((address_space(3))) unsigned int*)lds, 16, 0, 0);
}

// derive BN scale/shift for one channel from raw sums
__device__ __forceinline__ void bn_derive(const float* __restrict__ stats, const float* __restrict__ g,
                                          const float* __restrict__ b, float invM, int c,
                                          float& sc, float& sh) {
    float mu = stats[c] * invM;
    float var = stats[HH + c] * invM - mu * mu;
    float rstd = rsqrtf(var + BN_EPS);
    sc = rstd * g[c];
    sh = b[c] - mu * sc;
}

// ---------------- embed -> f16 ----------------
__global__ void embed_kernel(const float* __restrict__ xa, const float* __restrict__ xp,
                             const float* __restrict__ aw, const float* __restrict__ ab,
                             const float* __restrict__ pw, const float* __restrict__ pb,
                             unsigned short* __restrict__ h, int N) {
    int n = blockIdx.x;
    int c = threadIdx.x;
    if (n >= N) return;
    float acc = ab[c] + pb[c];
#pragma unroll
    for (int k = 0; k < 9; ++k) acc += xa[n * 9 + k] * aw[k * HH + c];
#pragma unroll
    for (int k = 0; k < 8; ++k) acc += xp[n * 8 + k] * pw[k * HH + c];
    h[(size_t)n * HH + c] = f2h(acc);
}

// ---------------- CSR build ----------------
__global__ void zero_int_kernel(int* __restrict__ p, int n) {
    int i = blockIdx.x * blockDim.x + threadIdx.x;
    if (i < n) p[i] = 0;
}

__global__ void hist_kernel(const int* __restrict__ ei, int* __restrict__ deg, int E) {
    int e = blockIdx.x * blockDim.x + threadIdx.x;
    if (e < E) atomicAdd(&deg[ei[(size_t)E + e]], 1);
}

__global__ void ps1_kernel(const int* __restrict__ deg, int* __restrict__ chunkSum, int N) {
    __shared__ int sm[CHUNK];
    int i = blockIdx.x * CHUNK + threadIdx.x;
    sm[threadIdx.x] = (i < N) ? deg[i] : 0;
    __syncthreads();
    for (int off = CHUNK / 2; off > 0; off >>= 1) {
        if (threadIdx.x < off) sm[threadIdx.x] += sm[threadIdx.x + off];
        __syncthreads();
    }
    if (threadIdx.x == 0) chunkSum[blockIdx.x] = sm[0];
}

__global__ void ps2_kernel(const int* __restrict__ chunkSum, int* __restrict__ chunkOff,
                           int nc, int* __restrict__ offs, int N, int E) {
    __shared__ int sm[CHUNK];
    int t = threadIdx.x;
    int own = (t < nc) ? chunkSum[t] : 0;
    sm[t] = own;
    for (int off = 1; off < CHUNK; off <<= 1) {
        __syncthreads();
        int v = (t >= off) ? sm[t - off] : 0;
        __syncthreads();
        sm[t] += v;
    }
    if (t < nc) chunkOff[t] = sm[t] - own;
    if (t == 0) offs[N] = E;
}

__global__ void ps3_kernel(const int* __restrict__ deg, const int* __restrict__ chunkOff,
                           int* __restrict__ offs, int* __restrict__ cursor, int N) {
    __shared__ int sm[CHUNK];
    int t = threadIdx.x;
    int i = blockIdx.x * CHUNK + t;
    int own = (i < N) ? deg[i] : 0;
    sm[t] = own;
    for (int off = 1; off < CHUNK; off <<= 1) {
        __syncthreads();
        int v = (t >= off) ? sm[t - off] : 0;
        __syncthreads();
        sm[t] += v;
    }
    if (i < N) {
        int o = chunkOff[blockIdx.x] + sm[t] - own;
        offs[i] = o;
        cursor[i] = o;
    }
}

__global__ void fill_kernel(const int* __restrict__ ei, int* __restrict__ cursor,
                            int* __restrict__ srcl, int E) {
    int e = blockIdx.x * blockDim.x + threadIdx.x;
    if (e >= E) return;
    int s = ei[e];
    int d = ei[(size_t)E + e];
    int pos = atomicAdd(&cursor[d], 1);
    srcl[pos] = s;
}

// ---------------- W transpose: Wt[n][k] = f16(W[k][n]) ----------------
__global__ void transpose_w_kernel(const float* __restrict__ W, unsigned short* __restrict__ Wt) {
    __shared__ float tile[32][33];
    int mat = blockIdx.x >> 6, t = blockIdx.x & 63;
    int kt = (t >> 3) * 32, nt = (t & 7) * 32;
    const float* Wm = W + (size_t)mat * HH * HH;
    unsigned short* Wtm = Wt + (size_t)mat * HH * HH;
    int lx = threadIdx.x & 31, ly = threadIdx.x >> 5;
#pragma unroll
    for (int yy = 0; yy < 32; yy += 8)
        tile[ly + yy][lx] = Wm[(size_t)(kt + ly + yy) * HH + nt + lx];
    __syncthreads();
#pragma unroll
    for (int yy = 0; yy < 32; yy += 8)
        Wtm[(size_t)(nt + ly + yy) * HH + kt + lx] = f2h(tile[lx][ly + yy]);
}

// ---------------- stats init: zero sum regions of all slots ----------------
__global__ void init_stats_kernel(float* __restrict__ stats) {
    int i = blockIdx.x * blockDim.x + threadIdx.x;
    int slot = i >> 9;
    if (slot < NSLOT) stats[(size_t)slot * 4 * HH + (i & 511)] = 0.f;
}

// ---------------- fused aggregation: z[n] = t(x[n]) + sum t(x[src_j]) ----------------
// t(x) = relu(x*sc+sh) when stats != null (x = raw GEMM2 output), else identity.
// BN finalize inlined (raw sums -> sc/sh per lane).
__global__ __launch_bounds__(256) void aggregate_fused_kernel(
        const unsigned short* __restrict__ h,
        const int* __restrict__ offs, const int* __restrict__ srcl,
        const float* __restrict__ stats, const float* __restrict__ gv,
        const float* __restrict__ bv, float invM,
        unsigned short* __restrict__ z, int N) {
    int n = blockIdx.x * 4 + (threadIdx.x >> 6);
    int l = threadIdx.x & 63;
    if (n >= N) return;
    int c = l * 4;
    const bool apply = (stats != nullptr);
    float sc0 = 1.f, sc1 = 1.f, sc2 = 1.f, sc3 = 1.f;
    float sh0 = 0.f, sh1 = 0.f, sh2 = 0.f, sh3 = 0.f;
    if (apply) {
        bn_derive(stats, gv, bv, invM, c + 0, sc0, sh0);
        bn_derive(stats, gv, bv, invM, c + 1, sc1, sh1);
        bn_derive(stats, gv, bv, invM, c + 2, sc2, sh2);
        bn_derive(stats, gv, bv, invM, c + 3, sc3, sh3);
    }

#define LOADT(row, r0, r1, r2, r3)                                   \
    {                                                                \
        ushort4 v_ = *(const ushort4*)&h[(size_t)(row) * HH + c];    \
        r0 = h2f(v_.x); r1 = h2f(v_.y); r2 = h2f(v_.z); r3 = h2f(v_.w); \
        if (apply) {                                                 \
            r0 = fmaxf(r0 * sc0 + sh0, 0.f);                         \
            r1 = fmaxf(r1 * sc1 + sh1, 0.f);                         \
            r2 = fmaxf(r2 * sc2 + sh2, 0.f);                         \
            r3 = fmaxf(r3 * sc3 + sh3, 0.f);                         \
        }                                                            \
    }

    float a0, a1, a2, a3;
    LOADT(n, a0, a1, a2, a3);
    int s0 = offs[n], s1 = offs[n + 1];
    int j = s0;
    for (; j + 2 <= s1; j += 2) {
        int ra = srcl[j], rb = srcl[j + 1];
        float t0, t1, t2, t3, u0, u1, u2, u3;
        LOADT(ra, t0, t1, t2, t3);
        LOADT(rb, u0, u1, u2, u3);
        a0 += t0 + u0; a1 += t1 + u1; a2 += t2 + u2; a3 += t3 + u3;
    }
    if (j < s1) {
        float t0, t1, t2, t3;
        LOADT(srcl[j], t0, t1, t2, t3);
        a0 += t0; a1 += t1; a2 += t2; a3 += t3;
    }
#undef LOADT
    ushort4 o;
    o.x = f2h(a0); o.y = f2h(a1); o.z = f2h(a2); o.w = f2h(a3);
    *(ushort4*)&z[(size_t)n * HH + c] = o;
}

// ---------------- f16 MFMA GEMM + fused BN partial stats ----------------
// Tile 128x128, BK=64, 4 waves (2x2). LDS [128][64]f16 per matrix with 16B-granule
// XOR swizzle (g ^= row&7); staging pre-swizzles the GLOBAL source (rule #21).
__global__ __launch_bounds__(256) void mfma_gemm_kernel(const unsigned short* __restrict__ A,
                                                        const unsigned short* __restrict__ Wt,
                                                        const float* __restrict__ bias,
                                                        unsigned short* __restrict__ C,
                                                        float* __restrict__ stats,
                                                        int M) {
    __shared__ unsigned short As[128 * 64];
    __shared__ unsigned short Bs[128 * 64];
    int tid = threadIdx.x;
    int w = tid >> 6, l = tid & 63;
    int wr = w >> 1, wc = w & 1;
    int row0 = blockIdx.x * 128;
    int col0 = blockIdx.y * 128;
    int g = (l & 7) ^ (l >> 3);      // pre-swizzled source granule
    int srow = w * 8 + (l >> 3);

    f32x4 acc[4][4] = {};

    const unsigned short* AB = A + (size_t)row0 * HH;
    const unsigned short* WB = Wt + (size_t)col0 * HH;

    for (int k0 = 0; k0 < 256; k0 += 64) {
#pragma unroll
        for (int r = 0; r < 4; ++r) {
            int row = r * 32 + srow;
            size_t go = (size_t)row * HH + k0 + g * 8;
            int lo = (r * 32 + w * 8) * 64;
            gload16(AB + go, &As[lo]);
            gload16(WB + go, &Bs[lo]);
        }
        __syncthreads();
#pragma unroll
        for (int kh = 0; kh < 2; ++kh) {
            f16x8 af[4], bf[4];
#pragma unroll
            for (int m = 0; m < 4; ++m) {
                int rr = wr * 64 + m * 16 + (l & 15);
                int gs = (kh * 4 + (l >> 4)) ^ (rr & 7);
                af[m] = *(const f16x8*)&As[rr * 64 + gs * 8];
            }
#pragma unroll
            for (int n = 0; n < 4; ++n) {
                int rr = wc * 64 + n * 16 + (l & 15);
                int gs = (kh * 4 + (l >> 4)) ^ (rr & 7);
                bf[n] = *(const f16x8*)&Bs[rr * 64 + gs * 8];
            }
#pragma unroll
            for (int m = 0; m < 4; ++m)
#pragma unroll
                for (int n = 0; n < 4; ++n)
                    acc[m][n] = __builtin_amdgcn_mfma_f32_16x16x32_f16(af[m], bf[n], acc[m][n], 0, 0, 0);
        }
        __syncthreads();
    }

    int mvalid = M - row0;
#pragma unroll
    for (int n = 0; n < 4; ++n) {
        int col = col0 + wc * 64 + n * 16 + (l & 15);
        float bvv = bias[col];
        float s = 0.f, s2 = 0.f;
#pragma unroll
        for (int m = 0; m < 4; ++m) {
            int rb = wr * 64 + m * 16 + (l >> 4) * 4;
#pragma unroll
            for (int r = 0; r < 4; ++r) {
                if (rb + r < mvalid) {
                    float v = acc[m][n][r] + bvv;
                    C[(size_t)(row0 + rb + r) * HH + col] = f2h(v);
                    s += v;
                    s2 += v * v;
                }
            }
        }
        s += __shfl_xor(s, 16);   s += __shfl_xor(s, 32);
        s2 += __shfl_xor(s2, 16); s2 += __shfl_xor(s2, 32);
        if ((l >> 4) == 0) {
            atomicAdd(&stats[col], s);
            atomicAdd(&stats[HH + col], s2);
        }
    }
}

// ---------------- BN helpers ----------------
__global__ void bn_stats_kernel(const float* __restrict__ X, int M, float* __restrict__ stats) {
    int c = threadIdx.x;
    int r0 = blockIdx.x * 128;
    int r1 = min(r0 + 128, M);
    float s = 0.f, s2 = 0.f;
    for (int r = r0; r < r1; ++r) {
        float v = X[(size_t)r * HH + c];
        s += v;
        s2 += v * v;
    }
    atomicAdd(&stats[c], s);
    atomicAdd(&stats[HH + c], s2);
}

__global__ void bn_finalize_kernel(float* __restrict__ stats, const float* __restrict__ g,
                                   const float* __restrict__ b, float invM) {
    int c = threadIdx.x;
    float sc, sh;
    bn_derive(stats, g, b, invM, c, sc, sh);
    stats[2 * HH + c] = sc;
    stats[3 * HH + c] = sh;
}

// f16 in-place: x = relu(x*sc + sh), 8 elems/thread; finalize inlined
__global__ void bn_apply_relu_f16_kernel(unsigned short* __restrict__ X, int n8,
                                         const float* __restrict__ stats,
                                         const float* __restrict__ gv,
                                         const float* __restrict__ bv, float invM) {
    int i = blockIdx.x * blockDim.x + threadIdx.x;
    int stride = gridDim.x * blockDim.x;
    for (; i < n8; i += stride) {
        int c0 = (i & 31) * 8;
        uint4 raw = *(const uint4*)&X[(size_t)i * 8];
        unsigned short hx[8], out[8];
        *(uint4*)hx = raw;
#pragma unroll
        for (int t = 0; t < 8; ++t) {
            float sc, sh;
            bn_derive(stats, gv, bv, invM, c0 + t, sc, sh);
            float y = fmaxf(h2f(hx[t]) * sc + sh, 0.f);
            out[t] = f2h(y);
        }
        *(uint4*)&X[(size_t)i * 8] = *(uint4*)out;
    }
}

// classifier-only f32 in-place apply (uses precomputed sc/sh)
__global__ void bn_apply_relu_kernel(float* __restrict__ X, int n4, const float* __restrict__ stats) {
    int i = blockIdx.x * blockDim.x + threadIdx.x;
    int stride = gridDim.x * blockDim.x;
    for (; i < n4; i += stride) {
        int c4 = (i & 63) * 4;
        float4 v = ((float4*)X)[i];
        float4 sc = *(const float4*)&stats[2 * HH + c4];
        float4 sh = *(const float4*)&stats[3 * HH + c4];
        v.x = fmaxf(v.x * sc.x + sh.x, 0.f);
        v.y = fmaxf(v.y * sc.y + sh.y, 0.f);
        v.z = fmaxf(v.z * sc.z + sh.z, 0.f);
        v.w = fmaxf(v.w * sc.w + sh.w, 0.f);
        ((float4*)X)[i] = v;
    }
}

// ---------------- f32 GEMM (classifier only) ----------------
__global__ __launch_bounds__(256) void gemm_kernel(const float* __restrict__ A,
                                                   const float* __restrict__ W,
                                                   const float* __restrict__ bias,
                                                   float* __restrict__ C,
                                                   int M, int ldw) {
    __shared__ float Asm[64][33];
    __shared__ float Wsm[32][64];
    int tid = threadIdx.x;
    int tx = tid & 15, ty = tid >> 4;
    int row0 = blockIdx.x * 64;
    int col0 = blockIdx.y * 64;
    float acc[4][4] = {};

    for (int k0 = 0; k0 < 256; k0 += 32) {
#pragma unroll
        for (int t = 0; t < 2; ++t) {
            int s = tid + t * 256;
            int m = s >> 3;
            int kq = (s & 7) * 4;
            float4 v = make_float4(0.f, 0.f, 0.f, 0.f);
            if (row0 + m < M) v = *(const float4*)&A[(size_t)(row0 + m) * 256 + k0 + kq];
            Asm[m][kq + 0] = v.x; Asm[m][kq + 1] = v.y; Asm[m][kq + 2] = v.z; Asm[m][kq + 3] = v.w;
        }
#pragma unroll
        for (int t = 0; t < 2; ++t) {
            int s = tid + t * 256;
            int kk = s >> 4;
            int cq = (s & 15) * 4;
            *(float4*)&Wsm[kk][cq] = *(const float4*)&W[(size_t)(k0 + kk) * ldw + col0 + cq];
        }
        __syncthreads();
#pragma unroll
        for (int kk = 0; kk < 32; ++kk) {
            float a0 = Asm[ty * 4 + 0][kk];
            float a1 = Asm[ty * 4 + 1][kk];
            float a2 = Asm[ty * 4 + 2][kk];
            float a3 = Asm[ty * 4 + 3][kk];
            float4 wv = *(const float4*)&Wsm[kk][tx * 4];
            acc[0][0] += a0 * wv.x; acc[0][1] += a0 * wv.y; acc[0][2] += a0 * wv.z; acc[0][3] += a0 * wv.w;
            acc[1][0] += a1 * wv.x; acc[1][1] += a1 * wv.y; acc[1][2] += a1 * wv.z; acc[1][3] += a1 * wv.w;
            acc[2][0] += a2 * wv.x; acc[2][1] += a2 * wv.y; acc[2][2] += a2 * wv.z; acc[2][3] += a2 * wv.w;
            acc[3][0] += a3 * wv.x; acc[3][1] += a3 * wv.y; acc[3][2] += a3 * wv.z; acc[3][3] += a3 * wv.w;
        }
        __syncthreads();
    }

    float4 bvv = *(const float4*)&bias[col0 + tx * 4];
#pragma unroll
    for (int j = 0; j < 4; ++j) {
        int row = row0 + ty * 4 + j;
        if (row < M) {
            float4 o = make_float4(acc[j][0] + bvv.x, acc[j][1] + bvv.y,
                                   acc[j][2] + bvv.z, acc[j][3] + bvv.w);
            *(float4*)&C[(size_t)row * ldw + col0 + tx * 4] = o;
        }
    }
}

// ---------------- fused mean pool: pooled = mean relu(bn(z2_last)) ----------------
__device__ __forceinline__ int lbound(const int* a, int n, int v) {
    int lo = 0, hi = n;
    while (lo < hi) {
        int mid = (lo + hi) >> 1;
        if (a[mid] < v) lo = mid + 1; else hi = mid;
    }
    return lo;
}

__global__ void pool_fused_kernel(const unsigned short* __restrict__ Hm,
                                  const int* __restrict__ batch,
                                  const float* __restrict__ stats,
                                  const float* __restrict__ gv,
                                  const float* __restrict__ bv, float invM,
                                  int N, float* __restrict__ pooled) {
    int g = blockIdx.x;
    int c = threadIdx.x;
    int s = lbound(batch, N, g);
    int e = lbound(batch, N, g + 1);
    float sc, sh;
    bn_derive(stats, gv, bv, invM, c, sc, sh);
    float acc = 0.f;
    for (int r = s; r < e; ++r)
        acc += fmaxf(h2f(Hm[(size_t)r * HH + c]) * sc + sh, 0.f);
    pooled[(size_t)g * HH + c] = acc / (float)max(e - s, 1);
}

// ---------------- launch ----------------
extern "C" void kernel_launch(void* const* d_in, const int* in_sizes, int n_in,
                              void* d_out, int out_size, void* d_ws, size_t ws_size,
                              hipStream_t stream) {
    const float* x_atom = (const float*)d_in[0];
    const float* x_pe   = (const float*)d_in[1];
    const int* ei       = (const int*)d_in[2];
    const int* batch    = (const int*)d_in[3];
    const float* ae_w = (const float*)d_in[4];
    const float* ae_b = (const float*)d_in[5];
    const float* pe_w = (const float*)d_in[6];
    const float* pe_b = (const float*)d_in[7];
    const float* w1  = (const float*)d_in[8];
    const float* b1  = (const float*)d_in[9];
    const float* g1  = (const float*)d_in[10];
    const float* be1 = (const float*)d_in[11];
    const float* w2  = (const float*)d_in[12];
    const float* b2  = (const float*)d_in[13];
    const float* bng = (const float*)d_in[14];
    const float* bnb = (const float*)d_in[15];
    const float* cl1_w = (const float*)d_in[16];
    const float* cl1_b = (const float*)d_in[17];
    const float* clg = (const float*)d_in[18];
    const float* clb = (const float*)d_in[19];
    const float* cl2_w = (const float*)d_in[20];
    const float* cl2_b = (const float*)d_in[21];

    const int N = in_sizes[3];
    const int E = in_sizes[2] / 2;
    const int T = in_sizes[21];
    const int B = out_size / T;
    const int Lnum = in_sizes[9] / HH;
    const int nc = cdiv(N, CHUNK);
    const int Npad = cdiv(N, 128) * 128;
    const size_t P = (size_t)Npad * HH;

    unsigned short* X = (unsigned short*)d_ws;
    unsigned short* Y = X + P;
    unsigned short* wt1 = Y + P;                        // L*HH*HH f16
    unsigned short* wt2 = wt1 + (size_t)Lnum * HH * HH;
    float* stats = (float*)(wt2 + (size_t)Lnum * HH * HH);   // NSLOT x 4*HH
    float* pooled = stats + (size_t)NSLOT * 4 * HH;
    float* zc = pooled + (size_t)B * HH;
    int* deg = (int*)(zc + (size_t)B * HH);
    int* offs = deg + N;
    int* cursor = offs + N + 1;
    int* chunkSum = cursor + N;
    int* chunkOff = chunkSum + 256;
    int* srcl = chunkOff + 256;

    const int n8 = N * (HH / 8);
    const int BH4 = B * (HH / 4);
    const float invN = 1.f / (float)N;

    // ---- CSR build ----
    zero_int_kernel<<<cdiv(N, 256), 256, 0, stream>>>(deg, N);
    hist_kernel<<<cdiv(E, 256), 256, 0, stream>>>(ei, deg, E);
    ps1_kernel<<<nc, CHUNK, 0, stream>>>(deg, chunkSum, N);
    ps2_kernel<<<1, CHUNK, 0, stream>>>(chunkSum, chunkOff, nc, offs, N, E);
    ps3_kernel<<<nc, CHUNK, 0, stream>>>(deg, chunkOff, offs, cursor, N);
    fill_kernel<<<cdiv(E, 256), 256, 0, stream>>>(ei, cursor, srcl, E);

    // ---- weight transpose (f32 -> f16, [k][n] -> [n][k]) ----
    transpose_w_kernel<<<Lnum * 64, 256, 0, stream>>>(w1, wt1);
    transpose_w_kernel<<<Lnum * 64, 256, 0, stream>>>(w2, wt2);

    // ---- stats init (all slots, once) ----
    init_stats_kernel<<<cdiv(NSLOT * 512, 256), 256, 0, stream>>>(stats);

    // ---- embed ----
    embed_kernel<<<N, HH, 0, stream>>>(x_atom, x_pe, ae_w, ae_b, pe_w, pe_b, X, N);

    dim3 mf_grid(cdiv(N, 128), 2);
    int apply_blocks = min(2048, cdiv(n8, 256));

    unsigned short *in = X, *ot = Y;

    for (int i = 0; i < Lnum; ++i) {
        float* slot1 = stats + (size_t)(2 * i) * 4 * HH;
        float* slot2 = stats + (size_t)(2 * i + 1) * 4 * HH;
        const float* aggStats = (i == 0) ? nullptr : stats + (size_t)(2 * i - 1) * 4 * HH;
        const float* aggG = (i == 0) ? nullptr : bng + (size_t)(i - 1) * HH;
        const float* aggB = (i == 0) ? nullptr : bnb + (size_t)(i - 1) * HH;

        // z = t(in) + gather-sum t(in[src]) : in -> ot
        aggregate_fused_kernel<<<cdiv(N, 4), 256, 0, stream>>>(in, offs, srcl,
                                                               aggStats, aggG, aggB, invN, ot, N);

        // z1 = z @ w1 + b1 : ot -> in ; inner BN+relu in place
        mfma_gemm_kernel<<<mf_grid, 256, 0, stream>>>(ot, wt1 + (size_t)i * HH * HH,
                                                      b1 + (size_t)i * HH, in, slot1, N);
        bn_apply_relu_f16_kernel<<<apply_blocks, 256, 0, stream>>>(in, n8, slot1,
                                                                   g1 + (size_t)i * HH,
                                                                   be1 + (size_t)i * HH, invN);

        // z2 = a1 @ w2 + b2 : in -> ot (raw; outer BN fused into next consumer)
        mfma_gemm_kernel<<<mf_grid, 256, 0, stream>>>(in, wt2 + (size_t)i * HH * HH,
                                                      b2 + (size_t)i * HH, ot, slot2, N);

        unsigned short* t = in; in = ot; ot = t;
    }

    // ---- fused mean pool (applies last outer BN+relu) ----
    pool_fused_kernel<<<B, HH, 0, stream>>>(in, batch,
                                            stats + (size_t)(2 * Lnum - 1) * 4 * HH,
                                            bng + (size_t)(Lnum - 1) * HH,
                                            bnb + (size_t)(Lnum - 1) * HH, invN, N, pooled);

    // ---- classifier (f32 path, slot 10) ----
    float* slotC = stats + (size_t)10 * 4 * HH;
    dim3 cls_grid1(cdiv(B, 64), HH / 64);
    gemm_kernel<<<cls_grid1, 256, 0, stream>>>(pooled, cl1_w, cl1_b, zc, B, HH);
    bn_stats_kernel<<<cdiv(B, 128), HH, 0, stream>>>(zc, B, slotC);
    bn_finalize_kernel<<<1, HH, 0, stream>>>(slotC, clg, clb, 1.f / B);
    bn_apply_relu_kernel<<<min(2048, cdiv(BH4, 256)), 256, 0, stream>>>(zc, BH4, slotC);

    dim3 cls_grid2(cdiv(B, 64), T / 64);
    gemm_kernel<<<cls_grid2, 256, 0, stream>>>(zc, cl2_w, cl2_b, (float*)d_out, B, T);
}